// Round 4
// baseline (679.408 us; speedup 1.0000x reference)
//
#include <hip/hip_runtime.h>
#include <hip/hip_fp16.h>
#include <hip/hip_cooperative_groups.h>

namespace cg = cooperative_groups;

// ---------------------------------------------------------------------------
// GCN forward on MI355X — round 22.
//  * ONE cooperative megakernel replaces the 9-launch pipeline.  R21
//    accounting: layers 86us + final 2us + ~130us for six partition kernels
//    whose essential traffic is ~45MB (~8us at HBM rate) -> ~85us of launch
//    overhead.  Fix dispatch count, not traffic.
//  * totals+scan_bb+scanB collapsed into one "alloc" phase: CSR bucket
//    regions need only be DISJOINT, not ordered -> one wave per bucket does
//    the 64-lane block-prefix over its hist column and atomically allocates
//    its pairbuf slice (pcur) and padded csr region (ccur, slack included,
//    16B aligned).  Removes two global barriers outright.
//  * All phases grid-stride (grid sized by occupancy query x CU count, so
//    cooperative co-residency is guaranteed by construction).  Non-coop
//    fallback: launch the same kernel 7x with a phase selector.
//  * Write-locality lessons kept (R20): placement still flows through
//    block-private LDS cursors / per-bucket LDS staging.
// ---------------------------------------------------------------------------

#define DD 64
#define BKT 256
#define MAXK 1024        // hist/cur row stride (K <= 1024)
#define NBLK 256         // edge chunks (hist rows)
#define SRCMASK 0x3FFFF  // low 18 bits = src node id
#define PBUF_CAP 3072    // LDS staging capacity (bucket max ~2.3k, lambda 2046)
#define SMEM_INTS 3840   // 15360 B: max over phases (build: 768 + 3072 ints)

typedef _Float16 half8_t __attribute__((ext_vector_type(8)));
typedef float float4_t __attribute__((ext_vector_type(4)));
union F4H8 { float4 f; half8_t h; };
union H8   { float4 f; __half2 h[4]; };

static __device__ __forceinline__ void atomAddF(float* p, float v) {
    unsafeAtomicAdd(p, v);   // global_atomic_add_f32 on gfx950
}

struct Params {
    const int* x; const int* src; const int* dst; const int* batch;
    const float2* table2; const float* W1; const float* b1;
    const float* W2; const float* b2; const float* Wlin; const float* blin;
    float* out;
    __half* g1h; __half* th; __half* w1t; __half* w2t;
    int* pairbuf; int* csr; int2* rowinfo; float2* xd; __half* dinvh;
    float* outacc; int* pbase; int* pcnt; int* cbase; int* pcur; int* ccur;
    int* hist; int* cur;
    int N, E, G, TBL, K, CH;
};

// ---- phase 0: zero cursors/outacc, fp16 conversions, per-chunk histogram --
static __device__ void phase_prep(const Params& P, int* smem) {
    int tid = threadIdx.x;
    int gid = blockIdx.x * 256 + tid;
    int gstride = gridDim.x * 256;
    if (gid == 0) { *P.pcur = 0; *P.ccur = 0; }
    for (int i = gid; i < 2 * P.G; i += gstride) P.outacc[i] = 0.f;
    __half2* th2 = (__half2*)P.th;
    int n2 = P.TBL / 2;
    for (int i = gid; i < n2; i += gstride)
        th2[i] = __float22half2_rn(P.table2[i]);
    for (int i = gid; i < DD * DD; i += gstride) {
        int n = i >> 6, k = i & 63;
        P.w1t[i] = __float2half(P.W1[k * DD + n]);   // WT[n][k]
        P.w2t[i] = __float2half(P.W2[k * DD + n]);
    }
    int* lh = smem;
    for (int c = blockIdx.x; c < NBLK; c += gridDim.x) {
        for (int i = tid; i < P.K; i += 256) lh[i] = 0;
        __syncthreads();
        int e0 = c * P.CH, e1 = min(P.E, e0 + P.CH);
        for (int e = e0 + tid; e < e1; e += 256)
            atomicAdd(&lh[((unsigned)P.dst[e]) >> 8], 1);
        __syncthreads();
        for (int b = tid; b < P.K; b += 256) P.hist[c * MAXK + b] = lh[b];
        __syncthreads();
    }
}

// ---- phase 1: one WAVE per bucket: block-prefix + atomic region alloc -----
static __device__ void phase_alloc(const Params& P) {
    int w = (blockIdx.x * 256 + threadIdx.x) >> 6;
    int lane = threadIdx.x & 63;
    int nw = (gridDim.x * 256) >> 6;
    const int PER = NBLK / 64;   // 4 chunks per lane
    for (int b = w; b < P.K; b += nw) {
        int v[PER];
        int sum = 0;
        #pragma unroll
        for (int i = 0; i < PER; ++i) {
            v[i] = P.hist[(lane * PER + i) * MAXK + b];
            sum += v[i];
        }
        int pref = sum;
        #pragma unroll
        for (int off = 1; off < 64; off <<= 1) {
            int t = __shfl_up(pref, off);
            if (lane >= off) pref += t;
        }
        int total = __shfl(pref, 63);
        int pb = 0;
        if (lane == 0) {
            pb = atomicAdd(P.pcur, total);
            int cb = atomicAdd(P.ccur, ((total + 3) & ~3) + 3 * BKT);
            P.pbase[b] = pb;
            P.pcnt[b]  = total;
            P.cbase[b] = cb;   // multiple of 4 ints -> rows stay 16B aligned
        }
        pb = __shfl(pb, 0);
        int run = pb + pref - sum;   // exclusive
        #pragma unroll
        for (int i = 0; i < PER; ++i) {
            P.cur[(lane * PER + i) * MAXK + b] = run;
            run += v[i];
        }
    }
}

// ---- phase 2: append packed pairs; cursors in LDS (block-private cells) ---
static __device__ void phase_fill(const Params& P, int* smem) {
    int tid = threadIdx.x;
    int* lcur = smem;
    for (int c = blockIdx.x; c < NBLK; c += gridDim.x) {
        for (int b = tid; b < P.K; b += 256) lcur[b] = P.cur[c * MAXK + b];
        __syncthreads();
        int e0 = c * P.CH, e1 = min(P.E, e0 + P.CH);
        for (int e = e0 + tid; e < e1; e += 256) {
            int s = P.src[e], d = P.dst[e];
            int pos = atomicAdd(&lcur[((unsigned)d) >> 8], 1);
            P.pairbuf[pos] = s | ((d & 255) << 24);
        }
        __syncthreads();
    }
}

// ---- phase 3: per-bucket CSR build from LDS-staged slice ------------------
// csr entry = src | (x[src] << 18).  Sentinel pad = N.
static __device__ void phase_build(const Params& P, int* smem) {
    int tid = threadIdx.x;
    int* cnt  = smem;
    int* excl = smem + 256;
    int* curl = smem + 512;
    int* pbuf = smem + 768;
    for (int b = blockIdx.x; b < P.K; b += gridDim.x) {
        int node0 = b << 8;
        cnt[tid] = 0;
        __syncthreads();
        int bb0 = P.pbase[b];
        int L   = P.pcnt[b];
        bool fits = (L <= PBUF_CAP);
        if (fits) {
            for (int i = tid; i < L; i += 256) {
                int pk = P.pairbuf[bb0 + i];
                pbuf[i] = pk;
                atomicAdd(&cnt[((unsigned)pk) >> 24], 1);
            }
        } else {
            for (int i = tid; i < L; i += 256)
                atomicAdd(&cnt[((unsigned)P.pairbuf[bb0 + i]) >> 24], 1);
        }
        __syncthreads();
        int c  = cnt[tid];
        int pc = (c + 3) & ~3;
        __syncthreads();
        excl[tid] = pc;
        __syncthreads();
        if (tid < 64) {
            int carry = 0;
            for (int cc = 0; cc < 4; ++cc) {
                int orig = excl[cc * 64 + tid];
                int v = orig;
                #pragma unroll
                for (int off = 1; off < 64; off <<= 1) {
                    int t = __shfl_up(v, off);
                    if (tid >= off) v += t;
                }
                int tot = __shfl(v, 63);
                cnt[cc * 64 + tid] = v - orig + carry;   // exclusive
                carry += tot;
            }
        }
        __syncthreads();
        int cb0 = P.cbase[b];
        int node = node0 + tid;
        int myBase = cb0 + cnt[tid];
        curl[tid] = myBase;
        if (node < P.N) {
            P.rowinfo[node] = make_int2(myBase, pc);
            float di = rsqrtf((float)c + 1.0f);
            P.xd[node] = make_float2(di, __int_as_float(P.x[node]));
            P.dinvh[node] = __float2half(di);
            for (int t = c; t < pc; ++t) P.csr[myBase + t] = P.N;
        } else if (node == P.N) {
            P.xd[P.N] = make_float2(0.0f, __int_as_float(0));
            P.dinvh[P.N] = __float2half(0.0f);
            float2* z = (float2*)(P.g1h + (size_t)P.N * DD);
            for (int t = 0; t < DD / 4; ++t) z[t] = make_float2(0.f, 0.f);
        }
        __syncthreads();
        if (fits) {
            for (int i = tid; i < L; i += 256) {
                int pk = pbuf[i];
                int pos = atomicAdd(&curl[((unsigned)pk) >> 24], 1);
                int s = pk & 0x00FFFFFF;
                P.csr[pos] = (int)(((unsigned)s) | (((unsigned)P.x[s]) << 18));
            }
        } else {
            for (int i = tid; i < L; i += 256) {
                int pk = P.pairbuf[bb0 + i];
                int pos = atomicAdd(&curl[((unsigned)pk) >> 24], 1);
                int s = pk & 0x00FFFFFF;
                P.csr[pos] = (int)(((unsigned)s) | (((unsigned)P.x[s]) << 18));
            }
        }
        __syncthreads();
    }
}

// ---- phase 4: layer 1 (embed+agg from fp16 table, MFMA MLP, g1h out) ------
static __device__ void phase_layer1(const Params& P, int* smem) {
    float4* Hs4 = (float4*)smem;            // 32*9 float4
    float*  dvs = (float*)(smem + 1152);    // 32 floats
    const float4* th4 = (const float4*)P.th;
    const float4* WT4 = (const float4*)P.w1t;
    int tid = threadIdx.x;
    int node_l = tid >> 3, j3 = tid & 7;
    int wave = tid >> 6, lane = tid & 63;
    int m = lane & 15, quad = lane >> 4;
    int ncol = wave * 16 + m;
    F4H8 b0, b1;
    b0.f = WT4[ncol * 8 + quad];
    b1.f = WT4[ncol * 8 + 4 + quad];
    float bb_ = P.b1[ncol];
    int T = (P.N + 31) >> 5;
    for (int tile = blockIdx.x; tile < T; tile += gridDim.x) {
        int row0 = tile << 5;
        int node = row0 + node_l;
        H8 acc0, acc1, acc2, acc3;
        acc0.f = make_float4(0.f, 0.f, 0.f, 0.f);
        acc1.f = acc0.f; acc2.f = acc0.f; acc3.f = acc0.f;
        __half2 dh = __float2half2_rn(0.f);
        if (node < P.N) {
            float2 sxd = P.xd[node];
            float di = sxd.x;
            if (j3 == 0) dvs[node_l] = di;
            dh = __float2half2_rn(di);
            H8 tv; tv.f = th4[(size_t)__float_as_int(sxd.y) * 8 + j3];
            acc0.h[0] = __hmul2(dh, tv.h[0]); acc0.h[1] = __hmul2(dh, tv.h[1]);
            acc0.h[2] = __hmul2(dh, tv.h[2]); acc0.h[3] = __hmul2(dh, tv.h[3]);
            int2 ri = P.rowinfo[node];
            const int4* cs = (const int4*)(P.csr + ri.x);
            int nq = ri.y >> 2;
            int q = 0;
            for (; q + 1 < nq; q += 2) {
                int4 sA = cs[q], sB = cs[q + 1];
                unsigned a0 = (unsigned)sA.x, a1 = (unsigned)sA.y;
                unsigned a2 = (unsigned)sA.z, a3 = (unsigned)sA.w;
                unsigned e0 = (unsigned)sB.x, e1 = (unsigned)sB.y;
                unsigned e2 = (unsigned)sB.z, e3 = (unsigned)sB.w;
                H8 u0, u1, u2, u3, u4, u5, u6, u7;
                u0.f = th4[(size_t)(a0 >> 18) * 8 + j3];
                u1.f = th4[(size_t)(a1 >> 18) * 8 + j3];
                u2.f = th4[(size_t)(a2 >> 18) * 8 + j3];
                u3.f = th4[(size_t)(a3 >> 18) * 8 + j3];
                u4.f = th4[(size_t)(e0 >> 18) * 8 + j3];
                u5.f = th4[(size_t)(e1 >> 18) * 8 + j3];
                u6.f = th4[(size_t)(e2 >> 18) * 8 + j3];
                u7.f = th4[(size_t)(e3 >> 18) * 8 + j3];
                __half2 w0 = __half2half2(P.dinvh[a0 & SRCMASK]);
                __half2 w1 = __half2half2(P.dinvh[a1 & SRCMASK]);
                __half2 w2 = __half2half2(P.dinvh[a2 & SRCMASK]);
                __half2 w3 = __half2half2(P.dinvh[a3 & SRCMASK]);
                __half2 w4 = __half2half2(P.dinvh[e0 & SRCMASK]);
                __half2 w5 = __half2half2(P.dinvh[e1 & SRCMASK]);
                __half2 w6 = __half2half2(P.dinvh[e2 & SRCMASK]);
                __half2 w7 = __half2half2(P.dinvh[e3 & SRCMASK]);
                #pragma unroll
                for (int t = 0; t < 4; ++t) {
                    acc0.h[t] = __hfma2(w0, u0.h[t], acc0.h[t]);
                    acc1.h[t] = __hfma2(w1, u1.h[t], acc1.h[t]);
                    acc2.h[t] = __hfma2(w2, u2.h[t], acc2.h[t]);
                    acc3.h[t] = __hfma2(w3, u3.h[t], acc3.h[t]);
                    acc0.h[t] = __hfma2(w4, u4.h[t], acc0.h[t]);
                    acc1.h[t] = __hfma2(w5, u5.h[t], acc1.h[t]);
                    acc2.h[t] = __hfma2(w6, u6.h[t], acc2.h[t]);
                    acc3.h[t] = __hfma2(w7, u7.h[t], acc3.h[t]);
                }
            }
            if (q < nq) {
                int4 sA = cs[q];
                unsigned a0 = (unsigned)sA.x, a1 = (unsigned)sA.y;
                unsigned a2 = (unsigned)sA.z, a3 = (unsigned)sA.w;
                H8 u0, u1, u2, u3;
                u0.f = th4[(size_t)(a0 >> 18) * 8 + j3];
                u1.f = th4[(size_t)(a1 >> 18) * 8 + j3];
                u2.f = th4[(size_t)(a2 >> 18) * 8 + j3];
                u3.f = th4[(size_t)(a3 >> 18) * 8 + j3];
                __half2 w0 = __half2half2(P.dinvh[a0 & SRCMASK]);
                __half2 w1 = __half2half2(P.dinvh[a1 & SRCMASK]);
                __half2 w2 = __half2half2(P.dinvh[a2 & SRCMASK]);
                __half2 w3 = __half2half2(P.dinvh[a3 & SRCMASK]);
                #pragma unroll
                for (int t = 0; t < 4; ++t) {
                    acc0.h[t] = __hfma2(w0, u0.h[t], acc0.h[t]);
                    acc1.h[t] = __hfma2(w1, u1.h[t], acc1.h[t]);
                    acc2.h[t] = __hfma2(w2, u2.h[t], acc2.h[t]);
                    acc3.h[t] = __hfma2(w3, u3.h[t], acc3.h[t]);
                }
            }
            #pragma unroll
            for (int t = 0; t < 4; ++t)
                acc0.h[t] = __hmul2(dh, __hadd2(__hadd2(acc0.h[t], acc1.h[t]),
                                                __hadd2(acc2.h[t], acc3.h[t])));
        }
        Hs4[node_l * 9 + j3] = acc0.f;
        __syncthreads();
        #pragma unroll
        for (int t = 0; t < 2; ++t) {
            F4H8 a0, a1;
            a0.f = Hs4[(t * 16 + m) * 9 + quad];
            a1.f = Hs4[(t * 16 + m) * 9 + 4 + quad];
            float4_t acc = {0.f, 0.f, 0.f, 0.f};
            acc = __builtin_amdgcn_mfma_f32_16x16x32_f16(a0.h, b0.h, acc, 0, 0, 0);
            acc = __builtin_amdgcn_mfma_f32_16x16x32_f16(a1.h, b1.h, acc, 0, 0, 0);
            #pragma unroll
            for (int reg = 0; reg < 4; ++reg) {
                int row = t * 16 + quad * 4 + reg;
                int grow = row0 + row;
                if (grow < P.N) {
                    float h = fmaxf(acc[reg] + bb_, 0.0f);
                    P.g1h[(size_t)grow * DD + ncol] = __float2half(dvs[row] * h);
                }
            }
        }
        __syncthreads();   // Hs4/dvs reuse next tile
    }
}

// ---- phase 5: layer 2 + pool ----------------------------------------------
static __device__ void phase_layer2(const Params& P, int* smem) {
    float4* Hs4 = (float4*)smem;              // 1152 ints
    float*  lp0 = (float*)(smem + 1152);      // 128
    float*  lp1 = (float*)(smem + 1280);      // 128
    float*  p0s = (float*)(smem + 1408);      // 32
    float*  p1s = (float*)(smem + 1440);      // 32
    int*    bat = smem + 1472;                // 32
    const float4* g1h4 = (const float4*)P.g1h;
    const float4* WT4  = (const float4*)P.w2t;
    int tid = threadIdx.x;
    int node_l = tid >> 3, j3 = tid & 7;
    int wave = tid >> 6, lane = tid & 63;
    int m = lane & 15, quad = lane >> 4;
    int ncol = wave * 16 + m;
    F4H8 b0, b1;
    b0.f = WT4[ncol * 8 + quad];
    b1.f = WT4[ncol * 8 + 4 + quad];
    float bb_ = P.b2[ncol];
    float wl0 = P.Wlin[ncol * 2 + 0];
    float wl1 = P.Wlin[ncol * 2 + 1];
    int T = (P.N + 31) >> 5;
    for (int tile = blockIdx.x; tile < T; tile += gridDim.x) {
        int row0 = tile << 5;
        int node = row0 + node_l;
        H8 acc0, acc1, acc2, acc3;
        acc0.f = make_float4(0.f, 0.f, 0.f, 0.f);
        acc1.f = acc0.f; acc2.f = acc0.f; acc3.f = acc0.f;
        if (node < P.N) {
            float di = P.xd[node].x;
            acc0.f = g1h4[(size_t)node * 8 + j3];   // self term, weight 1
            int2 ri = P.rowinfo[node];
            const int4* cs = (const int4*)(P.csr + ri.x);
            int nq = ri.y >> 2;
            int q = 0;
            for (; q + 1 < nq; q += 2) {
                int4 sA = cs[q], sB = cs[q + 1];
                H8 u0, u1, u2, u3, u4, u5, u6, u7;
                u0.f = g1h4[(size_t)(sA.x & SRCMASK) * 8 + j3];
                u1.f = g1h4[(size_t)(sA.y & SRCMASK) * 8 + j3];
                u2.f = g1h4[(size_t)(sA.z & SRCMASK) * 8 + j3];
                u3.f = g1h4[(size_t)(sA.w & SRCMASK) * 8 + j3];
                u4.f = g1h4[(size_t)(sB.x & SRCMASK) * 8 + j3];
                u5.f = g1h4[(size_t)(sB.y & SRCMASK) * 8 + j3];
                u6.f = g1h4[(size_t)(sB.z & SRCMASK) * 8 + j3];
                u7.f = g1h4[(size_t)(sB.w & SRCMASK) * 8 + j3];
                #pragma unroll
                for (int t = 0; t < 4; ++t) {
                    acc0.h[t] = __hadd2(acc0.h[t], u0.h[t]);
                    acc1.h[t] = __hadd2(acc1.h[t], u1.h[t]);
                    acc2.h[t] = __hadd2(acc2.h[t], u2.h[t]);
                    acc3.h[t] = __hadd2(acc3.h[t], u3.h[t]);
                    acc0.h[t] = __hadd2(acc0.h[t], u4.h[t]);
                    acc1.h[t] = __hadd2(acc1.h[t], u5.h[t]);
                    acc2.h[t] = __hadd2(acc2.h[t], u6.h[t]);
                    acc3.h[t] = __hadd2(acc3.h[t], u7.h[t]);
                }
            }
            if (q < nq) {
                int4 sA = cs[q];
                H8 u0, u1, u2, u3;
                u0.f = g1h4[(size_t)(sA.x & SRCMASK) * 8 + j3];
                u1.f = g1h4[(size_t)(sA.y & SRCMASK) * 8 + j3];
                u2.f = g1h4[(size_t)(sA.z & SRCMASK) * 8 + j3];
                u3.f = g1h4[(size_t)(sA.w & SRCMASK) * 8 + j3];
                #pragma unroll
                for (int t = 0; t < 4; ++t) {
                    acc0.h[t] = __hadd2(acc0.h[t], u0.h[t]);
                    acc1.h[t] = __hadd2(acc1.h[t], u1.h[t]);
                    acc2.h[t] = __hadd2(acc2.h[t], u2.h[t]);
                    acc3.h[t] = __hadd2(acc3.h[t], u3.h[t]);
                }
            }
            __half2 dih = __float2half2_rn(di);
            #pragma unroll
            for (int t = 0; t < 4; ++t)
                acc0.h[t] = __hmul2(dih, __hadd2(__hadd2(acc0.h[t], acc1.h[t]),
                                                 __hadd2(acc2.h[t], acc3.h[t])));
        }
        Hs4[node_l * 9 + j3] = acc0.f;
        __syncthreads();
        #pragma unroll
        for (int t = 0; t < 2; ++t) {
            F4H8 a0, a1;
            a0.f = Hs4[(t * 16 + m) * 9 + quad];
            a1.f = Hs4[(t * 16 + m) * 9 + 4 + quad];
            float4_t acc = {0.f, 0.f, 0.f, 0.f};
            acc = __builtin_amdgcn_mfma_f32_16x16x32_f16(a0.h, b0.h, acc, 0, 0, 0);
            acc = __builtin_amdgcn_mfma_f32_16x16x32_f16(a1.h, b1.h, acc, 0, 0, 0);
            #pragma unroll
            for (int reg = 0; reg < 4; ++reg) {
                int row = t * 16 + quad * 4 + reg;
                int grow = row0 + row;
                float h = (grow < P.N) ? fmaxf(acc[reg] + bb_, 0.0f) : 0.0f;
                float p0 = h * wl0;
                float p1 = h * wl1;
                #pragma unroll
                for (int off = 8; off >= 1; off >>= 1) {
                    p0 += __shfl_xor(p0, off);
                    p1 += __shfl_xor(p1, off);
                }
                if (m == 0) {
                    lp0[wave * 32 + row] = p0;
                    lp1[wave * 32 + row] = p1;
                }
            }
        }
        __syncthreads();
        if (tid < 32) {
            int grow = row0 + tid;
            p0s[tid] = lp0[tid] + lp0[32 + tid] + lp0[64 + tid] + lp0[96 + tid];
            p1s[tid] = lp1[tid] + lp1[32 + tid] + lp1[64 + tid] + lp1[96 + tid];
            bat[tid] = (grow < P.N) ? P.batch[grow] : -1;
        }
        __syncthreads();
        if (tid < 32) {
            int bg = bat[tid];
            bool head = (bg >= 0) && (tid == 0 || bat[tid - 1] != bg);
            if (head) {
                float s0 = 0.f, s1 = 0.f;
                for (int k = tid; k < 32 && bat[k] == bg; ++k) {
                    s0 += p0s[k];
                    s1 += p1s[k];
                }
                atomAddF(&P.outacc[bg * 2 + 0], s0);
                atomAddF(&P.outacc[bg * 2 + 1], s1);
            }
        }
        __syncthreads();   // lp/bat reuse next tile
    }
}

// ---- phase 6: counts via binary search; divide + blin ---------------------
static __device__ void phase_final(const Params& P) {
    int gid = blockIdx.x * 256 + threadIdx.x;
    int gstride = gridDim.x * 256;
    for (int t = gid; t < P.G * 2; t += gstride) {
        int g = t >> 1, c = t & 1;
        int lo = 0, hi = P.N;
        while (lo < hi) { int mm = (lo + hi) >> 1; if (P.batch[mm] < g) lo = mm + 1; else hi = mm; }
        int lo2 = lo, hi2 = P.N;
        while (lo2 < hi2) { int mm = (lo2 + hi2) >> 1; if (P.batch[mm] < g + 1) lo2 = mm + 1; else hi2 = mm; }
        float cnt = (float)(lo2 - lo);
        P.out[t] = P.outacc[t] / fmaxf(cnt, 1.0f) + P.blin[c];
    }
}

// ---- the megakernel -------------------------------------------------------
__global__ __launch_bounds__(256, 4) void megakernel(Params P, int phase) {
    __shared__ __align__(16) int smem[SMEM_INTS];
    bool all = (phase < 0);
    cg::grid_group grid = cg::this_grid();
    if (all || phase == 0) phase_prep(P, smem);
    if (all) grid.sync();
    if (all || phase == 1) phase_alloc(P);
    if (all) grid.sync();
    if (all || phase == 2) phase_fill(P, smem);
    if (all) grid.sync();
    if (all || phase == 3) phase_build(P, smem);
    if (all) grid.sync();
    if (all || phase == 4) phase_layer1(P, smem);
    if (all) grid.sync();
    if (all || phase == 5) phase_layer2(P, smem);
    if (all) grid.sync();
    if (all || phase == 6) phase_final(P);
}

extern "C" void kernel_launch(void* const* d_in, const int* in_sizes, int n_in,
                              void* d_out, int out_size, void* d_ws, size_t ws_size,
                              hipStream_t stream) {
    const int N = in_sizes[0];
    const int E = in_sizes[2];
    const int G = out_size / 2;
    const int TBL = in_sizes[4];
    const int K = (N + BKT - 1) / BKT;
    const int CH = (E + NBLK - 1) / NBLK;
    const int CSRSZ = E + (3 * BKT + 4) * K + 64;
    const int M = NBLK * MAXK;

    Params P;
    P.x = (const int*)d_in[0];
    P.src = (const int*)d_in[1];
    P.dst = ((const int*)d_in[1]) + E;
    P.batch = (const int*)d_in[3];
    P.table2 = (const float2*)d_in[4];
    P.W1 = (const float*)d_in[5];  P.b1 = (const float*)d_in[6];
    P.W2 = (const float*)d_in[7];  P.b2 = (const float*)d_in[8];
    P.Wlin = (const float*)d_in[9]; P.blin = (const float*)d_in[10];
    P.out = (float*)d_out;

    P.g1h   = (__half*)d_ws;                             // (N+1)*64 halves
    P.th    = P.g1h + (size_t)(N + 1) * DD;              // TBL halves
    P.w1t   = P.th + TBL;                                // 4096
    P.w2t   = P.w1t + DD * DD;                           // 4096
    P.pairbuf = (int*)(P.w2t + DD * DD);                 // E ints
    P.csr     = P.pairbuf + E;                           // CSRSZ ints
    P.rowinfo = (int2*)(P.csr + CSRSZ);                  // N int2
    P.xd      = (float2*)(P.rowinfo + N);                // N+1 float2
    P.dinvh   = (__half*)(P.xd + N + 1);                 // N+1 halves (pad even)
    P.outacc  = (float*)(P.dinvh + (size_t)((N + 2) & ~1));  // 2G floats
    P.pbase   = (int*)(P.outacc + 2 * G);                // K
    P.pcnt    = P.pbase + K;                             // K
    P.cbase   = P.pcnt + K;                              // K
    P.pcur    = P.cbase + K;                             // 1
    P.ccur    = P.pcur + 1;                              // 1 (+2 pad)
    P.hist    = P.ccur + 3;                              // M
    P.cur     = P.hist + M;                              // M

    P.N = N; P.E = E; P.G = G; P.TBL = TBL; P.K = K; P.CH = CH;

    static int s_grid = 0;
    static int s_coop = 0;
    if (s_grid == 0) {
        int coop = 0, dev = 0;
        hipGetDevice(&dev);
        hipDeviceGetAttribute(&coop, hipDeviceAttributeCooperativeLaunch, dev);
        int nb = 0;
        hipOccupancyMaxActiveBlocksPerMultiprocessor(&nb, megakernel, 256, 0);
        if (nb < 1) nb = 1;
        hipDeviceProp_t prop;
        hipGetDeviceProperties(&prop, dev);
        int cus = prop.multiProcessorCount;
        if (cus < 1) cus = 256;
        s_grid = nb * cus;
        s_coop = coop;
    }

    if (s_coop) {
        int phase = -1;
        void* args[] = {(void*)&P, (void*)&phase};
        hipLaunchCooperativeKernel(megakernel, dim3(s_grid), dim3(256),
                                   args, 0, stream);
    } else {
        for (int ph = 0; ph < 7; ++ph)
            hipLaunchKernelGGL(megakernel, dim3(s_grid), dim3(256), 0, stream,
                               P, ph);
    }
}

// Round 5
// 237.104 us; speedup vs baseline: 2.8655x; 2.8655x over previous
//
#include <hip/hip_runtime.h>
#include <hip/hip_fp16.h>

// ---------------------------------------------------------------------------
// GCN forward on MI355X — round 23.
//  * R22 post-mortem: coop megakernel = 679us with ALL pipes idle (VALU 2.9%,
//    HBM 2.7%) — grid-wide sync + one-size-fits-all launch shape loses badly
//    vs heterogeneous per-phase launches.  Reverted to the R21 skeleton
//    (218.2 us measured).
//  * Delta 1: totals+scan_bb+scanB merged into ONE alloc_kernel (proven
//    correct inside R22): csr bucket regions need only be DISJOINT, so one
//    wave per bucket block-prefixes its hist column and atomically allocates
//    its pairbuf slice (pcur) + padded csr region (ccur).  9 -> 7 launches.
//    outacc/pcur/ccur zeroing folded into bin_count.
//  * Delta 2: layer1/layer2 software-pipeline the cs[] chunk loads (prefetch
//    cs[q+2],cs[q+3] before the current body) — removes the ~200-400cy cs
//    L2 latency from the per-node serial chain.  +8 VGPR (32 -> ~40 < 64).
// ---------------------------------------------------------------------------

#define DD 64          // feature dim
#define BKT 256        // nodes per bucket (CSR build)
#define MAXK 1024      // max buckets; hist/cur row stride
#define NBLK 256       // partition blocks (chunks)
#define BTE 1024       // threads/block for per-edge passes
#define SRCMASK 0x3FFFF  // low 18 bits = src node id
#define PBUF_CAP 4096  // LDS staging capacity for one bucket's pair slice

typedef _Float16 half8_t __attribute__((ext_vector_type(8)));
typedef float float4_t __attribute__((ext_vector_type(4)));
union F4H8 { float4 f; half8_t h; };
union H8   { float4 f; __half2 h[4]; };

static __device__ __forceinline__ void atomAddF(float* p, float v) {
    unsafeAtomicAdd(p, v);   // global_atomic_add_f32 on gfx950
}

// ---- pass A: per-chunk histogram (+ fp16 conversions, cursor/outacc zero) -
__global__ __launch_bounds__(BTE) void bin_count_kernel(
        const int* __restrict__ dst, int E, int CH,
        int* __restrict__ hist, int K,
        const float2* __restrict__ table2, __half2* __restrict__ th2, int n2,
        const float* __restrict__ W1, const float* __restrict__ W2,
        __half* __restrict__ w1t, __half* __restrict__ w2t,
        float* __restrict__ outacc, int G2, int* __restrict__ pcur,
        int* __restrict__ ccur) {
    __shared__ int lh[MAXK];
    int tid = threadIdx.x;
    for (int i = tid; i < K; i += BTE) lh[i] = 0;
    __syncthreads();
    int gid = blockIdx.x * BTE + tid;
    int stride = gridDim.x * BTE;
    if (gid == 0) { *pcur = 0; *ccur = 0; }
    for (int i = gid; i < G2; i += stride) outacc[i] = 0.f;
    for (int i = gid; i < n2; i += stride)
        th2[i] = __float22half2_rn(table2[i]);
    for (int i = gid; i < DD * DD; i += stride) {
        int n = i >> 6, k = i & 63;
        w1t[i] = __float2half(W1[k * DD + n]);   // WT[n][k]
        w2t[i] = __float2half(W2[k * DD + n]);
    }
    int e0 = blockIdx.x * CH;
    int e1 = min(E, e0 + CH);
    for (int e = e0 + tid; e < e1; e += BTE)
        atomicAdd(&lh[((unsigned)dst[e]) >> 8], 1);
    __syncthreads();
    for (int b = tid; b < K; b += BTE)
        hist[blockIdx.x * MAXK + b] = lh[b];     // coalesced private row
}

// ---- pass B: one WAVE per bucket: prefix over hist column + atomic alloc --
// Replaces totals+scan_bb+scanB.  Regions need only be disjoint, not ordered.
__global__ __launch_bounds__(256) void alloc_kernel(
        const int* __restrict__ hist, int* __restrict__ cur,
        int* __restrict__ pbase, int* __restrict__ pcnt,
        int* __restrict__ cbase, int* __restrict__ pcur,
        int* __restrict__ ccur, int K) {
    int wid = (blockIdx.x * 256 + threadIdx.x) >> 6;   // wave id = bucket
    int lane = threadIdx.x & 63;
    if (wid >= K) return;
    const int PER = NBLK / 64;    // 4 chunks per lane
    int v[PER];
    int sum = 0;
    #pragma unroll
    for (int i = 0; i < PER; ++i) {
        v[i] = hist[(lane * PER + i) * MAXK + wid];
        sum += v[i];
    }
    int pref = sum;
    #pragma unroll
    for (int off = 1; off < 64; off <<= 1) {
        int t = __shfl_up(pref, off);
        if (lane >= off) pref += t;
    }
    int total = __shfl(pref, 63);
    int pb = 0;
    if (lane == 0) {
        pb = atomicAdd(pcur, total);
        int cb = atomicAdd(ccur, ((total + 3) & ~3) + 3 * BKT);
        pbase[wid] = pb;
        pcnt[wid]  = total;
        cbase[wid] = cb;   // multiple of 4 ints -> rows stay 16B aligned
    }
    pb = __shfl(pb, 0);
    int run = pb + pref - sum;   // exclusive
    #pragma unroll
    for (int i = 0; i < PER; ++i) {
        cur[(lane * PER + i) * MAXK + wid] = run;
        run += v[i];
    }
}

// ---- pass C: append packed pairs; cursors in LDS (block-private cells) ----
__global__ __launch_bounds__(BTE) void fill_kernel(
        const int* __restrict__ src, const int* __restrict__ dst, int E, int CH,
        const int* __restrict__ cur, int* __restrict__ pairbuf, int K) {
    __shared__ int lcur[MAXK];
    int tid = threadIdx.x;
    for (int b = tid; b < K; b += BTE)
        lcur[b] = cur[blockIdx.x * MAXK + b];
    __syncthreads();
    int e0 = blockIdx.x * CH;
    int e1 = min(E, e0 + CH);
    for (int e = e0 + tid; e < e1; e += BTE) {
        int s = src[e], d = dst[e];
        int pos = atomicAdd(&lcur[((unsigned)d) >> 8], 1);
        pairbuf[pos] = s | ((d & 255) << 24);
    }
}

// ---- pass D: per-bucket padded CSR build from LDS-staged slice ------------
// csr entry = src | (x[src] << 18).  Sentinel pad = N (x-part 0 -> zeroed th
// row 0, dinvh[N] = 0 -> zero weight, g1h row N zeroed -> zero layer2 term).
__global__ __launch_bounds__(256) void build_csr_kernel(
        const int* __restrict__ pairbuf, const int* __restrict__ pbase,
        const int* __restrict__ pcnt, const int* __restrict__ cbase,
        const int* __restrict__ x, int2* __restrict__ rowinfo,
        float2* __restrict__ xd, __half* __restrict__ dinvh,
        int* __restrict__ csr_src, __half* __restrict__ g1h, int N) {
    __shared__ int cnt[256], basel[256], curl[256];
    __shared__ int pbuf[PBUF_CAP];
    int tid = threadIdx.x;
    int b = blockIdx.x;
    int node0 = b << 8;
    cnt[tid] = 0;
    __syncthreads();
    int bb0 = pbase[b];
    int L   = pcnt[b];
    bool fits = (L <= PBUF_CAP);
    if (fits) {
        for (int i = tid; i < L; i += 256) {
            int pk = pairbuf[bb0 + i];
            pbuf[i] = pk;
            atomicAdd(&cnt[((unsigned)pk) >> 24], 1);
        }
    } else {
        for (int i = tid; i < L; i += 256)
            atomicAdd(&cnt[((unsigned)pairbuf[bb0 + i]) >> 24], 1);
    }
    __syncthreads();
    int c  = cnt[tid];
    int pc = (c + 3) & ~3;              // padded count
    {
        __syncthreads();
        basel[tid] = pc;
        __syncthreads();
        if (tid < 64) {
            int carry = 0;
            for (int cc = 0; cc < 4; ++cc) {
                int orig = basel[cc * 64 + tid];
                int v = orig;
                #pragma unroll
                for (int off = 1; off < 64; off <<= 1) {
                    int t = __shfl_up(v, off);
                    if (tid >= off) v += t;
                }
                int tot = __shfl(v, 63);
                cnt[cc * 64 + tid] = v - orig + carry;   // exclusive
                carry += tot;
            }
        }
        __syncthreads();
    }
    int cb0 = cbase[b];                 // 16B-aligned region from alloc
    int node = node0 + tid;
    int myBase = cb0 + cnt[tid];
    curl[tid] = myBase;
    if (node < N) {
        rowinfo[node] = make_int2(myBase, pc);
        float di = rsqrtf((float)c + 1.0f);
        xd[node] = make_float2(di, __int_as_float(x[node]));
        dinvh[node] = __float2half(di);
        for (int t = c; t < pc; ++t) csr_src[myBase + t] = N;   // sentinel pad
    } else if (node == N) {
        xd[N] = make_float2(0.0f, __int_as_float(0));           // zero weight
        dinvh[N] = __float2half(0.0f);
        float2* z = (float2*)(g1h + (size_t)N * DD);            // zero row N
        for (int t = 0; t < DD / 4; ++t) z[t] = make_float2(0.f, 0.f);
    }
    __syncthreads();
    if (fits) {
        for (int i = tid; i < L; i += 256) {
            int pk = pbuf[i];
            int pos = atomicAdd(&curl[((unsigned)pk) >> 24], 1);
            int s = pk & 0x00FFFFFF;
            csr_src[pos] = (int)(((unsigned)s) | (((unsigned)x[s]) << 18));
        }
    } else {
        for (int i = tid; i < L; i += 256) {
            int pk = pairbuf[bb0 + i];
            int pos = atomicAdd(&curl[((unsigned)pk) >> 24], 1);
            int s = pk & 0x00FFFFFF;
            csr_src[pos] = (int)(((unsigned)s) | (((unsigned)x[s]) << 18));
        }
    }
}

// ---------------- layer 1: agg from fp16 table, MFMA MLP, g1h = f16(dv*h1) --
// 8 lanes/node, b128 chunks; cs[] loads software-pipelined one iter ahead.
#define L1_BODY8(sA, sB)                                                      \
    do {                                                                      \
        unsigned a0 = (unsigned)(sA).x, a1 = (unsigned)(sA).y;                \
        unsigned a2 = (unsigned)(sA).z, a3 = (unsigned)(sA).w;                \
        unsigned b0i = (unsigned)(sB).x, b1i = (unsigned)(sB).y;              \
        unsigned b2i = (unsigned)(sB).z, b3i = (unsigned)(sB).w;              \
        H8 u0, u1, u2, u3, u4, u5, u6, u7;                                    \
        u0.f = th4[(size_t)(a0 >> 18) * 8 + j3];                              \
        u1.f = th4[(size_t)(a1 >> 18) * 8 + j3];                              \
        u2.f = th4[(size_t)(a2 >> 18) * 8 + j3];                              \
        u3.f = th4[(size_t)(a3 >> 18) * 8 + j3];                              \
        u4.f = th4[(size_t)(b0i >> 18) * 8 + j3];                             \
        u5.f = th4[(size_t)(b1i >> 18) * 8 + j3];                             \
        u6.f = th4[(size_t)(b2i >> 18) * 8 + j3];                             \
        u7.f = th4[(size_t)(b3i >> 18) * 8 + j3];                             \
        __half2 w0 = __half2half2(dinvh[a0 & SRCMASK]);                       \
        __half2 w1 = __half2half2(dinvh[a1 & SRCMASK]);                       \
        __half2 w2 = __half2half2(dinvh[a2 & SRCMASK]);                       \
        __half2 w3 = __half2half2(dinvh[a3 & SRCMASK]);                       \
        __half2 w4 = __half2half2(dinvh[b0i & SRCMASK]);                      \
        __half2 w5 = __half2half2(dinvh[b1i & SRCMASK]);                      \
        __half2 w6 = __half2half2(dinvh[b2i & SRCMASK]);                      \
        __half2 w7 = __half2half2(dinvh[b3i & SRCMASK]);                      \
        _Pragma("unroll")                                                     \
        for (int t = 0; t < 4; ++t) {                                         \
            acc0.h[t] = __hfma2(w0, u0.h[t], acc0.h[t]);                      \
            acc1.h[t] = __hfma2(w1, u1.h[t], acc1.h[t]);                      \
            acc2.h[t] = __hfma2(w2, u2.h[t], acc2.h[t]);                      \
            acc3.h[t] = __hfma2(w3, u3.h[t], acc3.h[t]);                      \
            acc0.h[t] = __hfma2(w4, u4.h[t], acc0.h[t]);                      \
            acc1.h[t] = __hfma2(w5, u5.h[t], acc1.h[t]);                      \
            acc2.h[t] = __hfma2(w6, u6.h[t], acc2.h[t]);                      \
            acc3.h[t] = __hfma2(w7, u7.h[t], acc3.h[t]);                      \
        }                                                                     \
    } while (0)

__global__ __launch_bounds__(256, 8) void layer1_kernel(
        const int2* __restrict__ rowinfo,
        const int* __restrict__ csr_src, const float2* __restrict__ xd,
        const __half* __restrict__ dinvh,
        const float4* __restrict__ th4, const __half* __restrict__ wt,
        const float* __restrict__ bias, __half* __restrict__ g1h, int N) {
    __shared__ float4 Hs4[32 * 9];   // padded stride 9
    __shared__ float dvs[32];
    int row0 = blockIdx.x * 32;
    int tid = threadIdx.x;
    int node_l = tid >> 3, j3 = tid & 7;
    int node = row0 + node_l;
    H8 acc0, acc1, acc2, acc3;
    acc0.f = make_float4(0.f, 0.f, 0.f, 0.f);
    acc1.f = acc0.f; acc2.f = acc0.f; acc3.f = acc0.f;
    __half2 dh = __float2half2_rn(0.f);
    if (node < N) {
        float2 sxd = xd[node];
        float di = sxd.x;
        if (j3 == 0) dvs[node_l] = di;
        dh = __float2half2_rn(di);
        H8 tv; tv.f = th4[(size_t)__float_as_int(sxd.y) * 8 + j3];
        acc0.h[0] = __hmul2(dh, tv.h[0]); acc0.h[1] = __hmul2(dh, tv.h[1]);
        acc0.h[2] = __hmul2(dh, tv.h[2]); acc0.h[3] = __hmul2(dh, tv.h[3]);
        int2 ri = rowinfo[node];
        const int4* cs = (const int4*)(csr_src + ri.x);
        int nq = ri.y >> 2;
        int q = 0;
        if (nq >= 2) {
            int4 sA = cs[0], sB = cs[1];
            for (; q + 3 < nq; q += 2) {
                int4 nA = cs[q + 2], nB = cs[q + 3];   // prefetch next pair
                L1_BODY8(sA, sB);
                sA = nA; sB = nB;
            }
            L1_BODY8(sA, sB);
            q += 2;
        }
        if (q < nq) {
            int4 sA = cs[q];
            unsigned a0 = (unsigned)sA.x, a1 = (unsigned)sA.y;
            unsigned a2 = (unsigned)sA.z, a3 = (unsigned)sA.w;
            H8 u0, u1, u2, u3;
            u0.f = th4[(size_t)(a0 >> 18) * 8 + j3];
            u1.f = th4[(size_t)(a1 >> 18) * 8 + j3];
            u2.f = th4[(size_t)(a2 >> 18) * 8 + j3];
            u3.f = th4[(size_t)(a3 >> 18) * 8 + j3];
            __half2 w0 = __half2half2(dinvh[a0 & SRCMASK]);
            __half2 w1 = __half2half2(dinvh[a1 & SRCMASK]);
            __half2 w2 = __half2half2(dinvh[a2 & SRCMASK]);
            __half2 w3 = __half2half2(dinvh[a3 & SRCMASK]);
            #pragma unroll
            for (int t = 0; t < 4; ++t) {
                acc0.h[t] = __hfma2(w0, u0.h[t], acc0.h[t]);
                acc1.h[t] = __hfma2(w1, u1.h[t], acc1.h[t]);
                acc2.h[t] = __hfma2(w2, u2.h[t], acc2.h[t]);
                acc3.h[t] = __hfma2(w3, u3.h[t], acc3.h[t]);
            }
        }
        #pragma unroll
        for (int t = 0; t < 4; ++t)
            acc0.h[t] = __hmul2(dh, __hadd2(__hadd2(acc0.h[t], acc1.h[t]),
                                            __hadd2(acc2.h[t], acc3.h[t])));
    }
    Hs4[node_l * 9 + j3] = acc0.f;
    __syncthreads();

    // MFMA MLP: 2 tiles of 16 rows; each wave does cols wave*16..+15, K=64.
    int wave = tid >> 6, lane = tid & 63;
    int m = lane & 15, quad = lane >> 4;
    int ncol = wave * 16 + m;
    F4H8 b0, b1;
    const float4* WT4 = (const float4*)wt;
    b0.f = WT4[ncol * 8 + quad];
    b1.f = WT4[ncol * 8 + 4 + quad];
    float bb_ = bias[ncol];
    #pragma unroll
    for (int t = 0; t < 2; ++t) {
        F4H8 a0, a1;
        a0.f = Hs4[(t * 16 + m) * 9 + quad];
        a1.f = Hs4[(t * 16 + m) * 9 + 4 + quad];
        float4_t acc = {0.f, 0.f, 0.f, 0.f};
        acc = __builtin_amdgcn_mfma_f32_16x16x32_f16(a0.h, b0.h, acc, 0, 0, 0);
        acc = __builtin_amdgcn_mfma_f32_16x16x32_f16(a1.h, b1.h, acc, 0, 0, 0);
        #pragma unroll
        for (int reg = 0; reg < 4; ++reg) {
            int row = t * 16 + quad * 4 + reg;
            int grow = row0 + row;
            if (grow < N) {
                float h = fmaxf(acc[reg] + bb_, 0.0f);
                g1h[(size_t)grow * DD + ncol] = __float2half(dvs[row] * h);
            }
        }
    }
}

// -------- layer 2 + pool: gather g1h, MFMA MLP, Wlin dot + segmented pool ---
#define L2_BODY8(sA, sB)                                                      \
    do {                                                                      \
        H8 u0, u1, u2, u3, u4, u5, u6, u7;                                    \
        u0.f = g1h4[(size_t)((sA).x & SRCMASK) * 8 + j3];                     \
        u1.f = g1h4[(size_t)((sA).y & SRCMASK) * 8 + j3];                     \
        u2.f = g1h4[(size_t)((sA).z & SRCMASK) * 8 + j3];                     \
        u3.f = g1h4[(size_t)((sA).w & SRCMASK) * 8 + j3];                     \
        u4.f = g1h4[(size_t)((sB).x & SRCMASK) * 8 + j3];                     \
        u5.f = g1h4[(size_t)((sB).y & SRCMASK) * 8 + j3];                     \
        u6.f = g1h4[(size_t)((sB).z & SRCMASK) * 8 + j3];                     \
        u7.f = g1h4[(size_t)((sB).w & SRCMASK) * 8 + j3];                     \
        _Pragma("unroll")                                                     \
        for (int t = 0; t < 4; ++t) {                                         \
            acc0.h[t] = __hadd2(acc0.h[t], u0.h[t]);                          \
            acc1.h[t] = __hadd2(acc1.h[t], u1.h[t]);                          \
            acc2.h[t] = __hadd2(acc2.h[t], u2.h[t]);                          \
            acc3.h[t] = __hadd2(acc3.h[t], u3.h[t]);                          \
            acc0.h[t] = __hadd2(acc0.h[t], u4.h[t]);                          \
            acc1.h[t] = __hadd2(acc1.h[t], u5.h[t]);                          \
            acc2.h[t] = __hadd2(acc2.h[t], u6.h[t]);                          \
            acc3.h[t] = __hadd2(acc3.h[t], u7.h[t]);                          \
        }                                                                     \
    } while (0)

__global__ __launch_bounds__(256, 8) void layer2_pool_kernel(
        const int2* __restrict__ rowinfo,
        const int* __restrict__ csr_src, const float2* __restrict__ xd,
        const float4* __restrict__ g1h4, const __half* __restrict__ wt,
        const float* __restrict__ bias, const int* __restrict__ batch,
        const float* __restrict__ Wlin, float* __restrict__ outacc, int N) {
    __shared__ float4 Hs4[32 * 9];       // padded stride 9
    __shared__ float lp0[128], lp1[128]; // [wave][row]
    __shared__ float p0s[32], p1s[32];
    __shared__ int   bat[32];
    int row0 = blockIdx.x * 32;
    int tid = threadIdx.x;
    int node_l = tid >> 3, j3 = tid & 7;
    int node = row0 + node_l;
    H8 acc0, acc1, acc2, acc3;
    acc0.f = make_float4(0.f, 0.f, 0.f, 0.f);
    acc1.f = acc0.f; acc2.f = acc0.f; acc3.f = acc0.f;
    if (node < N) {
        float di = xd[node].x;
        acc0.f = g1h4[(size_t)node * 8 + j3];   // self term, weight 1
        int2 ri = rowinfo[node];
        const int4* cs = (const int4*)(csr_src + ri.x);
        int nq = ri.y >> 2;
        int q = 0;
        if (nq >= 2) {
            int4 sA = cs[0], sB = cs[1];
            for (; q + 3 < nq; q += 2) {
                int4 nA = cs[q + 2], nB = cs[q + 3];   // prefetch next pair
                L2_BODY8(sA, sB);
                sA = nA; sB = nB;
            }
            L2_BODY8(sA, sB);
            q += 2;
        }
        if (q < nq) {
            int4 sA = cs[q];
            H8 u0, u1, u2, u3;
            u0.f = g1h4[(size_t)(sA.x & SRCMASK) * 8 + j3];
            u1.f = g1h4[(size_t)(sA.y & SRCMASK) * 8 + j3];
            u2.f = g1h4[(size_t)(sA.z & SRCMASK) * 8 + j3];
            u3.f = g1h4[(size_t)(sA.w & SRCMASK) * 8 + j3];
            #pragma unroll
            for (int t = 0; t < 4; ++t) {
                acc0.h[t] = __hadd2(acc0.h[t], u0.h[t]);
                acc1.h[t] = __hadd2(acc1.h[t], u1.h[t]);
                acc2.h[t] = __hadd2(acc2.h[t], u2.h[t]);
                acc3.h[t] = __hadd2(acc3.h[t], u3.h[t]);
            }
        }
        __half2 dih = __float2half2_rn(di);
        #pragma unroll
        for (int t = 0; t < 4; ++t)
            acc0.h[t] = __hmul2(dih, __hadd2(__hadd2(acc0.h[t], acc1.h[t]),
                                             __hadd2(acc2.h[t], acc3.h[t])));
    }
    Hs4[node_l * 9 + j3] = acc0.f;
    __syncthreads();

    int wave = tid >> 6, lane = tid & 63;
    int m = lane & 15, quad = lane >> 4;
    int ncol = wave * 16 + m;
    F4H8 b0, b1;
    const float4* WT4 = (const float4*)wt;
    b0.f = WT4[ncol * 8 + quad];
    b1.f = WT4[ncol * 8 + 4 + quad];
    float bb_  = bias[ncol];
    float wl0 = Wlin[ncol * 2 + 0];
    float wl1 = Wlin[ncol * 2 + 1];
    #pragma unroll
    for (int t = 0; t < 2; ++t) {
        F4H8 a0, a1;
        a0.f = Hs4[(t * 16 + m) * 9 + quad];
        a1.f = Hs4[(t * 16 + m) * 9 + 4 + quad];
        float4_t acc = {0.f, 0.f, 0.f, 0.f};
        acc = __builtin_amdgcn_mfma_f32_16x16x32_f16(a0.h, b0.h, acc, 0, 0, 0);
        acc = __builtin_amdgcn_mfma_f32_16x16x32_f16(a1.h, b1.h, acc, 0, 0, 0);
        #pragma unroll
        for (int reg = 0; reg < 4; ++reg) {
            int row = t * 16 + quad * 4 + reg;
            int grow = row0 + row;
            float h = (grow < N) ? fmaxf(acc[reg] + bb_, 0.0f) : 0.0f;
            float p0 = h * wl0;
            float p1 = h * wl1;
            #pragma unroll
            for (int off = 8; off >= 1; off >>= 1) {   // sum over 16 cols (m)
                p0 += __shfl_xor(p0, off);
                p1 += __shfl_xor(p1, off);
            }
            if (m == 0) {
                lp0[wave * 32 + row] = p0;
                lp1[wave * 32 + row] = p1;
            }
        }
    }
    __syncthreads();
    if (tid < 32) {
        int grow = row0 + tid;
        p0s[tid] = lp0[tid] + lp0[32 + tid] + lp0[64 + tid] + lp0[96 + tid];
        p1s[tid] = lp1[tid] + lp1[32 + tid] + lp1[64 + tid] + lp1[96 + tid];
        bat[tid] = (grow < N) ? batch[grow] : -1;
    }
    __syncthreads();
    if (tid < 32) {
        int bg = bat[tid];
        bool head = (bg >= 0) && (tid == 0 || bat[tid - 1] != bg);
        if (head) {
            float s0 = 0.f, s1 = 0.f;
            for (int k = tid; k < 32 && bat[k] == bg; ++k) {
                s0 += p0s[k];
                s1 += p1s[k];
            }
            atomAddF(&outacc[bg * 2 + 0], s0);
            atomAddF(&outacc[bg * 2 + 1], s1);
        }
    }
}

// counts via binary search on sorted batch; then divide + blin
__global__ void final_kernel(const float* __restrict__ outacc,
                             const int* __restrict__ batch,
                             const float* __restrict__ blin,
                             float* __restrict__ out, int G, int N) {
    int t = blockIdx.x * blockDim.x + threadIdx.x;
    if (t >= G * 2) return;
    int g = t >> 1, c = t & 1;
    int lo = 0, hi = N;
    while (lo < hi) { int m = (lo + hi) >> 1; if (batch[m] < g) lo = m + 1; else hi = m; }
    int lo2 = lo, hi2 = N;
    while (lo2 < hi2) { int m = (lo2 + hi2) >> 1; if (batch[m] < g + 1) lo2 = m + 1; else hi2 = m; }
    float cnt = (float)(lo2 - lo);
    out[t] = outacc[t] / fmaxf(cnt, 1.0f) + blin[c];
}

extern "C" void kernel_launch(void* const* d_in, const int* in_sizes, int n_in,
                              void* d_out, int out_size, void* d_ws, size_t ws_size,
                              hipStream_t stream) {
    const int*   x      = (const int*)d_in[0];
    const int*   ei     = (const int*)d_in[1];   // [2,E] row-major
    const int*   batch  = (const int*)d_in[3];
    const float* table  = (const float*)d_in[4];
    const float* W1     = (const float*)d_in[5];
    const float* b1     = (const float*)d_in[6];
    const float* W2     = (const float*)d_in[7];
    const float* b2     = (const float*)d_in[8];
    const float* Wlin   = (const float*)d_in[9];
    const float* blin   = (const float*)d_in[10];
    float* out = (float*)d_out;

    const int N = in_sizes[0];
    const int E = in_sizes[2];          // edge_type count == E
    const int G = out_size / 2;
    const int TBL = in_sizes[4];        // VOCAB*DD floats

    const int* src = ei;
    const int* dst = ei + E;

    const int K = (N + BKT - 1) / BKT;  // buckets
    const int M = NBLK * MAXK;          // (block, bucket) cells
    const int CH = (E + NBLK - 1) / NBLK;
    const int CSRSZ = E + (3 * BKT + 4) * K + 64;

    // workspace layout (keep 16-B alignment for b128 reads)
    __half* g1h     = (__half*)d_ws;                      // (N+1)*64 halves
    __half* th      = g1h + (size_t)(N + 1) * DD;         // TBL halves
    __half* w1t     = th + TBL;                           // 4096 halves
    __half* w2t     = w1t + DD * DD;                      // 4096 halves
    int*    pairbuf = (int*)(w2t + DD * DD);              // E ints
    int*    csr_src = pairbuf + E;                        // CSRSZ ints
    int2*   rowinfo = (int2*)(csr_src + CSRSZ);           // N int2
    float2* xd      = (float2*)(rowinfo + N);             // N+1 float2
    __half* dinvh   = (__half*)(xd + N + 1);              // N+1 halves (pad even)
    float*  outacc  = (float*)(dinvh + (size_t)((N + 2) & ~1)); // 2G
    int*    pbase   = (int*)(outacc + 2 * G);             // K
    int*    pcnt    = pbase + K;                          // K
    int*    cbase   = pcnt + K;                           // K
    int*    pcur    = cbase + K;                          // 1
    int*    ccur    = pcur + 1;                           // 1 (+2 pad)
    int*    hist    = ccur + 3;                           // M
    int*    cur     = hist + M;                           // M

    const int BT = 256;

    // partition: histogram(+zeros) -> alloc -> append -> CSR sort
    bin_count_kernel<<<NBLK, BTE, 0, stream>>>(dst, E, CH, hist, K,
                                               (const float2*)table,
                                               (__half2*)th, TBL / 2,
                                               W1, W2, w1t, w2t,
                                               outacc, 2 * G, pcur, ccur);
    alloc_kernel<<<(K * 64 + BT - 1) / BT, BT, 0, stream>>>(hist, cur, pbase,
                                                            pcnt, cbase, pcur,
                                                            ccur, K);
    fill_kernel<<<NBLK, BTE, 0, stream>>>(src, dst, E, CH, cur, pairbuf, K);
    build_csr_kernel<<<K, BT, 0, stream>>>(pairbuf, pbase, pcnt, cbase, x,
                                           rowinfo, xd, dinvh, csr_src, g1h, N);

    // layer 1 (embed+agg+MFMA-MLP+relu fused; writes g1h = fp16(dinv*h1))
    int gRow = (N + 31) / 32;
    layer1_kernel<<<gRow, BT, 0, stream>>>(rowinfo, csr_src, xd, dinvh,
                                           (const float4*)th, w1t, b1, g1h, N);
    // layer 2 (agg+MFMA-MLP+relu+pool fused)
    layer2_pool_kernel<<<gRow, BT, 0, stream>>>(rowinfo, csr_src, xd,
                                                (const float4*)g1h, w2t, b2,
                                                batch, Wlin, outacc, N);
    // final
    final_kernel<<<(G * 2 + BT - 1) / BT, BT, 0, stream>>>(outacc, batch, blin,
                                                           out, G, N);
}

// Round 6
// 230.519 us; speedup vs baseline: 2.9473x; 1.0286x over previous
//
#include <hip/hip_runtime.h>
#include <hip/hip_fp16.h>

// ---------------------------------------------------------------------------
// GCN forward on MI355X — round 24.
//  * R23 post-mortem: bundled {alloc merge, layer sw-pipelining} regressed
//    218.2 -> 237.1 us.  Layers stayed under ~44 us (all top-5 slots were
//    harness fills), but the manual cs[] rotation is the prime suspect —
//    forced prefetch-wait at iteration boundary + 4 extra live int4 tuples
//    vs the compiler's own load hoisting (same lesson as GEMM m131-m141:
//    don't hand-pipeline over a competent scheduler).
//  * R24 = clean A/B: layer1/layer2 reverted to the EXACT R21 bodies;
//    alloc_kernel merge (totals+scan_bb+scanB -> 1 kernel, 9 -> 7 launches)
//    kept.  outacc/pcur/ccur zeroing stays folded into bin_count.
// ---------------------------------------------------------------------------

#define DD 64          // feature dim
#define BKT 256        // nodes per bucket (CSR build)
#define MAXK 1024      // max buckets; hist/cur row stride
#define NBLK 256       // partition blocks (chunks)
#define BTE 1024       // threads/block for per-edge passes
#define SRCMASK 0x3FFFF  // low 18 bits = src node id
#define PBUF_CAP 4096  // LDS staging capacity for one bucket's pair slice

typedef _Float16 half8_t __attribute__((ext_vector_type(8)));
typedef float float4_t __attribute__((ext_vector_type(4)));
union F4H8 { float4 f; half8_t h; };
union H8   { float4 f; __half2 h[4]; };

static __device__ __forceinline__ void atomAddF(float* p, float v) {
    unsafeAtomicAdd(p, v);   // global_atomic_add_f32 on gfx950
}

// ---- pass A: per-chunk histogram (+ fp16 conversions, cursor/outacc zero) -
__global__ __launch_bounds__(BTE) void bin_count_kernel(
        const int* __restrict__ dst, int E, int CH,
        int* __restrict__ hist, int K,
        const float2* __restrict__ table2, __half2* __restrict__ th2, int n2,
        const float* __restrict__ W1, const float* __restrict__ W2,
        __half* __restrict__ w1t, __half* __restrict__ w2t,
        float* __restrict__ outacc, int G2, int* __restrict__ pcur,
        int* __restrict__ ccur) {
    __shared__ int lh[MAXK];
    int tid = threadIdx.x;
    for (int i = tid; i < K; i += BTE) lh[i] = 0;
    __syncthreads();
    int gid = blockIdx.x * BTE + tid;
    int stride = gridDim.x * BTE;
    if (gid == 0) { *pcur = 0; *ccur = 0; }
    for (int i = gid; i < G2; i += stride) outacc[i] = 0.f;
    for (int i = gid; i < n2; i += stride)
        th2[i] = __float22half2_rn(table2[i]);
    for (int i = gid; i < DD * DD; i += stride) {
        int n = i >> 6, k = i & 63;
        w1t[i] = __float2half(W1[k * DD + n]);   // WT[n][k]
        w2t[i] = __float2half(W2[k * DD + n]);
    }
    int e0 = blockIdx.x * CH;
    int e1 = min(E, e0 + CH);
    for (int e = e0 + tid; e < e1; e += BTE)
        atomicAdd(&lh[((unsigned)dst[e]) >> 8], 1);
    __syncthreads();
    for (int b = tid; b < K; b += BTE)
        hist[blockIdx.x * MAXK + b] = lh[b];     // coalesced private row
}

// ---- pass B: one WAVE per bucket: prefix over hist column + atomic alloc --
// Replaces totals+scan_bb+scanB.  Regions need only be disjoint, not ordered.
__global__ __launch_bounds__(256) void alloc_kernel(
        const int* __restrict__ hist, int* __restrict__ cur,
        int* __restrict__ pbase, int* __restrict__ pcnt,
        int* __restrict__ cbase, int* __restrict__ pcur,
        int* __restrict__ ccur, int K) {
    int wid = (blockIdx.x * 256 + threadIdx.x) >> 6;   // wave id = bucket
    int lane = threadIdx.x & 63;
    if (wid >= K) return;
    const int PER = NBLK / 64;    // 4 chunks per lane
    int v[PER];
    int sum = 0;
    #pragma unroll
    for (int i = 0; i < PER; ++i) {
        v[i] = hist[(lane * PER + i) * MAXK + wid];
        sum += v[i];
    }
    int pref = sum;
    #pragma unroll
    for (int off = 1; off < 64; off <<= 1) {
        int t = __shfl_up(pref, off);
        if (lane >= off) pref += t;
    }
    int total = __shfl(pref, 63);
    int pb = 0;
    if (lane == 0) {
        pb = atomicAdd(pcur, total);
        int cb = atomicAdd(ccur, ((total + 3) & ~3) + 3 * BKT);
        pbase[wid] = pb;
        pcnt[wid]  = total;
        cbase[wid] = cb;   // multiple of 4 ints -> rows stay 16B aligned
    }
    pb = __shfl(pb, 0);
    int run = pb + pref - sum;   // exclusive
    #pragma unroll
    for (int i = 0; i < PER; ++i) {
        cur[(lane * PER + i) * MAXK + wid] = run;
        run += v[i];
    }
}

// ---- pass C: append packed pairs; cursors in LDS (block-private cells) ----
__global__ __launch_bounds__(BTE) void fill_kernel(
        const int* __restrict__ src, const int* __restrict__ dst, int E, int CH,
        const int* __restrict__ cur, int* __restrict__ pairbuf, int K) {
    __shared__ int lcur[MAXK];
    int tid = threadIdx.x;
    for (int b = tid; b < K; b += BTE)
        lcur[b] = cur[blockIdx.x * MAXK + b];
    __syncthreads();
    int e0 = blockIdx.x * CH;
    int e1 = min(E, e0 + CH);
    for (int e = e0 + tid; e < e1; e += BTE) {
        int s = src[e], d = dst[e];
        int pos = atomicAdd(&lcur[((unsigned)d) >> 8], 1);
        pairbuf[pos] = s | ((d & 255) << 24);
    }
}

// ---- pass D: per-bucket padded CSR build from LDS-staged slice ------------
// csr entry = src | (x[src] << 18): layer1 decodes the embedding row directly,
// layer2 masks with SRCMASK.  Sentinel pad = N (x-part 0 -> zeroed th row 0,
// dinvh[N] = 0 -> zero weight, g1h row N zeroed -> zero layer2 term).
__global__ __launch_bounds__(256) void build_csr_kernel(
        const int* __restrict__ pairbuf, const int* __restrict__ pbase,
        const int* __restrict__ pcnt, const int* __restrict__ cbase,
        const int* __restrict__ x, int2* __restrict__ rowinfo,
        float2* __restrict__ xd, __half* __restrict__ dinvh,
        int* __restrict__ csr_src, __half* __restrict__ g1h, int N) {
    __shared__ int cnt[256], basel[256], curl[256];
    __shared__ int pbuf[PBUF_CAP];
    int tid = threadIdx.x;
    int b = blockIdx.x;
    int node0 = b << 8;
    cnt[tid] = 0;
    __syncthreads();
    int bb0 = pbase[b];
    int L   = pcnt[b];
    bool fits = (L <= PBUF_CAP);
    if (fits) {
        for (int i = tid; i < L; i += 256) {
            int pk = pairbuf[bb0 + i];
            pbuf[i] = pk;
            atomicAdd(&cnt[((unsigned)pk) >> 24], 1);
        }
    } else {
        for (int i = tid; i < L; i += 256)
            atomicAdd(&cnt[((unsigned)pairbuf[bb0 + i]) >> 24], 1);
    }
    __syncthreads();
    int c  = cnt[tid];
    int pc = (c + 3) & ~3;              // padded count
    {
        __syncthreads();
        basel[tid] = pc;
        __syncthreads();
        if (tid < 64) {
            int carry = 0;
            for (int cc = 0; cc < 4; ++cc) {
                int orig = basel[cc * 64 + tid];
                int v = orig;
                #pragma unroll
                for (int off = 1; off < 64; off <<= 1) {
                    int t = __shfl_up(v, off);
                    if (tid >= off) v += t;
                }
                int tot = __shfl(v, 63);
                cnt[cc * 64 + tid] = v - orig + carry;   // exclusive
                carry += tot;
            }
        }
        __syncthreads();
    }
    int cb0 = cbase[b];                 // 16B-aligned region from alloc
    int node = node0 + tid;
    int myBase = cb0 + cnt[tid];
    curl[tid] = myBase;
    if (node < N) {
        rowinfo[node] = make_int2(myBase, pc);
        float di = rsqrtf((float)c + 1.0f);
        xd[node] = make_float2(di, __int_as_float(x[node]));
        dinvh[node] = __float2half(di);
        for (int t = c; t < pc; ++t) csr_src[myBase + t] = N;   // sentinel pad
    } else if (node == N) {
        xd[N] = make_float2(0.0f, __int_as_float(0));           // zero weight
        dinvh[N] = __float2half(0.0f);
        float2* z = (float2*)(g1h + (size_t)N * DD);            // zero row N
        for (int t = 0; t < DD / 4; ++t) z[t] = make_float2(0.f, 0.f);
    }
    __syncthreads();
    if (fits) {
        for (int i = tid; i < L; i += 256) {
            int pk = pbuf[i];
            int pos = atomicAdd(&curl[((unsigned)pk) >> 24], 1);
            int s = pk & 0x00FFFFFF;
            csr_src[pos] = (int)(((unsigned)s) | (((unsigned)x[s]) << 18));
        }
    } else {
        for (int i = tid; i < L; i += 256) {
            int pk = pairbuf[bb0 + i];
            int pos = atomicAdd(&curl[((unsigned)pk) >> 24], 1);
            int s = pk & 0x00FFFFFF;
            csr_src[pos] = (int)(((unsigned)s) | (((unsigned)x[s]) << 18));
        }
    }
}

// ---------------- layer 1: agg from fp16 table, MFMA MLP, g1h = f16(dv*h1) --
// 8 lanes/node, b128 chunks; unroll x2; Hs stride 9 (bank-conflict pad).
// Packed-CSR decode: th row = entry >> 18, weight = dinvh[entry & SRCMASK]
// (independent 2B load, issues concurrently with the 16B th4 gather).
__global__ __launch_bounds__(256, 8) void layer1_kernel(
        const int2* __restrict__ rowinfo,
        const int* __restrict__ csr_src, const float2* __restrict__ xd,
        const __half* __restrict__ dinvh,
        const float4* __restrict__ th4, const __half* __restrict__ wt,
        const float* __restrict__ bias, __half* __restrict__ g1h, int N) {
    __shared__ float4 Hs4[32 * 9];   // padded stride 9
    __shared__ float dvs[32];
    int row0 = blockIdx.x * 32;
    int tid = threadIdx.x;
    int node_l = tid >> 3, j3 = tid & 7;
    int node = row0 + node_l;
    H8 acc0, acc1, acc2, acc3;
    acc0.f = make_float4(0.f, 0.f, 0.f, 0.f);
    acc1.f = acc0.f; acc2.f = acc0.f; acc3.f = acc0.f;
    __half2 dh = __float2half2_rn(0.f);
    if (node < N) {
        float2 sxd = xd[node];
        float di = sxd.x;
        if (j3 == 0) dvs[node_l] = di;
        dh = __float2half2_rn(di);
        H8 tv; tv.f = th4[(size_t)__float_as_int(sxd.y) * 8 + j3];
        acc0.h[0] = __hmul2(dh, tv.h[0]); acc0.h[1] = __hmul2(dh, tv.h[1]);
        acc0.h[2] = __hmul2(dh, tv.h[2]); acc0.h[3] = __hmul2(dh, tv.h[3]);
        int2 ri = rowinfo[node];
        const int4* cs = (const int4*)(csr_src + ri.x);
        int nq = ri.y >> 2;
        int q = 0;
        for (; q + 1 < nq; q += 2) {
            int4 sA = cs[q], sB = cs[q + 1];
            unsigned a0 = (unsigned)sA.x, a1 = (unsigned)sA.y;
            unsigned a2 = (unsigned)sA.z, a3 = (unsigned)sA.w;
            unsigned b0i = (unsigned)sB.x, b1i = (unsigned)sB.y;
            unsigned b2i = (unsigned)sB.z, b3i = (unsigned)sB.w;
            H8 u0, u1, u2, u3, u4, u5, u6, u7;
            u0.f = th4[(size_t)(a0 >> 18) * 8 + j3];
            u1.f = th4[(size_t)(a1 >> 18) * 8 + j3];
            u2.f = th4[(size_t)(a2 >> 18) * 8 + j3];
            u3.f = th4[(size_t)(a3 >> 18) * 8 + j3];
            u4.f = th4[(size_t)(b0i >> 18) * 8 + j3];
            u5.f = th4[(size_t)(b1i >> 18) * 8 + j3];
            u6.f = th4[(size_t)(b2i >> 18) * 8 + j3];
            u7.f = th4[(size_t)(b3i >> 18) * 8 + j3];
            __half2 w0 = __half2half2(dinvh[a0 & SRCMASK]);
            __half2 w1 = __half2half2(dinvh[a1 & SRCMASK]);
            __half2 w2 = __half2half2(dinvh[a2 & SRCMASK]);
            __half2 w3 = __half2half2(dinvh[a3 & SRCMASK]);
            __half2 w4 = __half2half2(dinvh[b0i & SRCMASK]);
            __half2 w5 = __half2half2(dinvh[b1i & SRCMASK]);
            __half2 w6 = __half2half2(dinvh[b2i & SRCMASK]);
            __half2 w7 = __half2half2(dinvh[b3i & SRCMASK]);
            #pragma unroll
            for (int t = 0; t < 4; ++t) {
                acc0.h[t] = __hfma2(w0, u0.h[t], acc0.h[t]);
                acc1.h[t] = __hfma2(w1, u1.h[t], acc1.h[t]);
                acc2.h[t] = __hfma2(w2, u2.h[t], acc2.h[t]);
                acc3.h[t] = __hfma2(w3, u3.h[t], acc3.h[t]);
                acc0.h[t] = __hfma2(w4, u4.h[t], acc0.h[t]);
                acc1.h[t] = __hfma2(w5, u5.h[t], acc1.h[t]);
                acc2.h[t] = __hfma2(w6, u6.h[t], acc2.h[t]);
                acc3.h[t] = __hfma2(w7, u7.h[t], acc3.h[t]);
            }
        }
        if (q < nq) {
            int4 sA = cs[q];
            unsigned a0 = (unsigned)sA.x, a1 = (unsigned)sA.y;
            unsigned a2 = (unsigned)sA.z, a3 = (unsigned)sA.w;
            H8 u0, u1, u2, u3;
            u0.f = th4[(size_t)(a0 >> 18) * 8 + j3];
            u1.f = th4[(size_t)(a1 >> 18) * 8 + j3];
            u2.f = th4[(size_t)(a2 >> 18) * 8 + j3];
            u3.f = th4[(size_t)(a3 >> 18) * 8 + j3];
            __half2 w0 = __half2half2(dinvh[a0 & SRCMASK]);
            __half2 w1 = __half2half2(dinvh[a1 & SRCMASK]);
            __half2 w2 = __half2half2(dinvh[a2 & SRCMASK]);
            __half2 w3 = __half2half2(dinvh[a3 & SRCMASK]);
            #pragma unroll
            for (int t = 0; t < 4; ++t) {
                acc0.h[t] = __hfma2(w0, u0.h[t], acc0.h[t]);
                acc1.h[t] = __hfma2(w1, u1.h[t], acc1.h[t]);
                acc2.h[t] = __hfma2(w2, u2.h[t], acc2.h[t]);
                acc3.h[t] = __hfma2(w3, u3.h[t], acc3.h[t]);
            }
        }
        #pragma unroll
        for (int t = 0; t < 4; ++t)
            acc0.h[t] = __hmul2(dh, __hadd2(__hadd2(acc0.h[t], acc1.h[t]),
                                            __hadd2(acc2.h[t], acc3.h[t])));
    }
    Hs4[node_l * 9 + j3] = acc0.f;
    __syncthreads();

    // MFMA MLP: 2 tiles of 16 rows; each wave does cols wave*16..+15, K=64.
    int wave = tid >> 6, lane = tid & 63;
    int m = lane & 15, quad = lane >> 4;
    int ncol = wave * 16 + m;
    F4H8 b0, b1;
    const float4* WT4 = (const float4*)wt;
    b0.f = WT4[ncol * 8 + quad];
    b1.f = WT4[ncol * 8 + 4 + quad];
    float bb_ = bias[ncol];
    #pragma unroll
    for (int t = 0; t < 2; ++t) {
        F4H8 a0, a1;
        a0.f = Hs4[(t * 16 + m) * 9 + quad];
        a1.f = Hs4[(t * 16 + m) * 9 + 4 + quad];
        float4_t acc = {0.f, 0.f, 0.f, 0.f};
        acc = __builtin_amdgcn_mfma_f32_16x16x32_f16(a0.h, b0.h, acc, 0, 0, 0);
        acc = __builtin_amdgcn_mfma_f32_16x16x32_f16(a1.h, b1.h, acc, 0, 0, 0);
        #pragma unroll
        for (int reg = 0; reg < 4; ++reg) {
            int row = t * 16 + quad * 4 + reg;
            int grow = row0 + row;
            if (grow < N) {
                float h = fmaxf(acc[reg] + bb_, 0.0f);
                g1h[(size_t)grow * DD + ncol] = __float2half(dvs[row] * h);
            }
        }
    }
}

// -------- layer 2 + pool: gather g1h, MFMA MLP, Wlin dot + segmented pool ---
__global__ __launch_bounds__(256, 8) void layer2_pool_kernel(
        const int2* __restrict__ rowinfo,
        const int* __restrict__ csr_src, const float2* __restrict__ xd,
        const float4* __restrict__ g1h4, const __half* __restrict__ wt,
        const float* __restrict__ bias, const int* __restrict__ batch,
        const float* __restrict__ Wlin, float* __restrict__ outacc, int N) {
    __shared__ float4 Hs4[32 * 9];       // padded stride 9
    __shared__ float lp0[128], lp1[128]; // [wave][row]
    __shared__ float p0s[32], p1s[32];
    __shared__ int   bat[32];
    int row0 = blockIdx.x * 32;
    int tid = threadIdx.x;
    int node_l = tid >> 3, j3 = tid & 7;
    int node = row0 + node_l;
    H8 acc0, acc1, acc2, acc3;
    acc0.f = make_float4(0.f, 0.f, 0.f, 0.f);
    acc1.f = acc0.f; acc2.f = acc0.f; acc3.f = acc0.f;
    if (node < N) {
        float di = xd[node].x;
        acc0.f = g1h4[(size_t)node * 8 + j3];   // self term, weight 1
        int2 ri = rowinfo[node];
        const int4* cs = (const int4*)(csr_src + ri.x);
        int nq = ri.y >> 2;
        int q = 0;
        for (; q + 1 < nq; q += 2) {
            int4 sA = cs[q], sB = cs[q + 1];
            H8 u0, u1, u2, u3, u4, u5, u6, u7;
            u0.f = g1h4[(size_t)(sA.x & SRCMASK) * 8 + j3];
            u1.f = g1h4[(size_t)(sA.y & SRCMASK) * 8 + j3];
            u2.f = g1h4[(size_t)(sA.z & SRCMASK) * 8 + j3];
            u3.f = g1h4[(size_t)(sA.w & SRCMASK) * 8 + j3];
            u4.f = g1h4[(size_t)(sB.x & SRCMASK) * 8 + j3];
            u5.f = g1h4[(size_t)(sB.y & SRCMASK) * 8 + j3];
            u6.f = g1h4[(size_t)(sB.z & SRCMASK) * 8 + j3];
            u7.f = g1h4[(size_t)(sB.w & SRCMASK) * 8 + j3];
            #pragma unroll
            for (int t = 0; t < 4; ++t) {
                acc0.h[t] = __hadd2(acc0.h[t], u0.h[t]);
                acc1.h[t] = __hadd2(acc1.h[t], u1.h[t]);
                acc2.h[t] = __hadd2(acc2.h[t], u2.h[t]);
                acc3.h[t] = __hadd2(acc3.h[t], u3.h[t]);
                acc0.h[t] = __hadd2(acc0.h[t], u4.h[t]);
                acc1.h[t] = __hadd2(acc1.h[t], u5.h[t]);
                acc2.h[t] = __hadd2(acc2.h[t], u6.h[t]);
                acc3.h[t] = __hadd2(acc3.h[t], u7.h[t]);
            }
        }
        if (q < nq) {
            int4 sA = cs[q];
            H8 u0, u1, u2, u3;
            u0.f = g1h4[(size_t)(sA.x & SRCMASK) * 8 + j3];
            u1.f = g1h4[(size_t)(sA.y & SRCMASK) * 8 + j3];
            u2.f = g1h4[(size_t)(sA.z & SRCMASK) * 8 + j3];
            u3.f = g1h4[(size_t)(sA.w & SRCMASK) * 8 + j3];
            #pragma unroll
            for (int t = 0; t < 4; ++t) {
                acc0.h[t] = __hadd2(acc0.h[t], u0.h[t]);
                acc1.h[t] = __hadd2(acc1.h[t], u1.h[t]);
                acc2.h[t] = __hadd2(acc2.h[t], u2.h[t]);
                acc3.h[t] = __hadd2(acc3.h[t], u3.h[t]);
            }
        }
        __half2 dih = __float2half2_rn(di);
        #pragma unroll
        for (int t = 0; t < 4; ++t)
            acc0.h[t] = __hmul2(dih, __hadd2(__hadd2(acc0.h[t], acc1.h[t]),
                                             __hadd2(acc2.h[t], acc3.h[t])));
    }
    Hs4[node_l * 9 + j3] = acc0.f;
    __syncthreads();

    int wave = tid >> 6, lane = tid & 63;
    int m = lane & 15, quad = lane >> 4;
    int ncol = wave * 16 + m;
    F4H8 b0, b1;
    const float4* WT4 = (const float4*)wt;
    b0.f = WT4[ncol * 8 + quad];
    b1.f = WT4[ncol * 8 + 4 + quad];
    float bb_  = bias[ncol];
    float wl0 = Wlin[ncol * 2 + 0];
    float wl1 = Wlin[ncol * 2 + 1];
    #pragma unroll
    for (int t = 0; t < 2; ++t) {
        F4H8 a0, a1;
        a0.f = Hs4[(t * 16 + m) * 9 + quad];
        a1.f = Hs4[(t * 16 + m) * 9 + 4 + quad];
        float4_t acc = {0.f, 0.f, 0.f, 0.f};
        acc = __builtin_amdgcn_mfma_f32_16x16x32_f16(a0.h, b0.h, acc, 0, 0, 0);
        acc = __builtin_amdgcn_mfma_f32_16x16x32_f16(a1.h, b1.h, acc, 0, 0, 0);
        #pragma unroll
        for (int reg = 0; reg < 4; ++reg) {
            int row = t * 16 + quad * 4 + reg;
            int grow = row0 + row;
            float h = (grow < N) ? fmaxf(acc[reg] + bb_, 0.0f) : 0.0f;
            float p0 = h * wl0;
            float p1 = h * wl1;
            #pragma unroll
            for (int off = 8; off >= 1; off >>= 1) {   // sum over 16 cols (m)
                p0 += __shfl_xor(p0, off);
                p1 += __shfl_xor(p1, off);
            }
            if (m == 0) {
                lp0[wave * 32 + row] = p0;
                lp1[wave * 32 + row] = p1;
            }
        }
    }
    __syncthreads();
    if (tid < 32) {
        int grow = row0 + tid;
        p0s[tid] = lp0[tid] + lp0[32 + tid] + lp0[64 + tid] + lp0[96 + tid];
        p1s[tid] = lp1[tid] + lp1[32 + tid] + lp1[64 + tid] + lp1[96 + tid];
        bat[tid] = (grow < N) ? batch[grow] : -1;
    }
    __syncthreads();
    if (tid < 32) {
        int bg = bat[tid];
        bool head = (bg >= 0) && (tid == 0 || bat[tid - 1] != bg);
        if (head) {
            float s0 = 0.f, s1 = 0.f;
            for (int k = tid; k < 32 && bat[k] == bg; ++k) {
                s0 += p0s[k];
                s1 += p1s[k];
            }
            atomAddF(&outacc[bg * 2 + 0], s0);
            atomAddF(&outacc[bg * 2 + 1], s1);
        }
    }
}

// counts via binary search on sorted batch; then divide + blin
__global__ void final_kernel(const float* __restrict__ outacc,
                             const int* __restrict__ batch,
                             const float* __restrict__ blin,
                             float* __restrict__ out, int G, int N) {
    int t = blockIdx.x * blockDim.x + threadIdx.x;
    if (t >= G * 2) return;
    int g = t >> 1, c = t & 1;
    int lo = 0, hi = N;
    while (lo < hi) { int m = (lo + hi) >> 1; if (batch[m] < g) lo = m + 1; else hi = m; }
    int lo2 = lo, hi2 = N;
    while (lo2 < hi2) { int m = (lo2 + hi2) >> 1; if (batch[m] < g + 1) lo2 = m + 1; else hi2 = m; }
    float cnt = (float)(lo2 - lo);
    out[t] = outacc[t] / fmaxf(cnt, 1.0f) + blin[c];
}

extern "C" void kernel_launch(void* const* d_in, const int* in_sizes, int n_in,
                              void* d_out, int out_size, void* d_ws, size_t ws_size,
                              hipStream_t stream) {
    const int*   x      = (const int*)d_in[0];
    const int*   ei     = (const int*)d_in[1];   // [2,E] row-major
    const int*   batch  = (const int*)d_in[3];
    const float* table  = (const float*)d_in[4];
    const float* W1     = (const float*)d_in[5];
    const float* b1     = (const float*)d_in[6];
    const float* W2     = (const float*)d_in[7];
    const float* b2     = (const float*)d_in[8];
    const float* Wlin   = (const float*)d_in[9];
    const float* blin   = (const float*)d_in[10];
    float* out = (float*)d_out;

    const int N = in_sizes[0];
    const int E = in_sizes[2];          // edge_type count == E
    const int G = out_size / 2;
    const int TBL = in_sizes[4];        // VOCAB*DD floats

    const int* src = ei;
    const int* dst = ei + E;

    const int K = (N + BKT - 1) / BKT;  // buckets
    const int M = NBLK * MAXK;          // (block, bucket) cells
    const int CH = (E + NBLK - 1) / NBLK;
    const int CSRSZ = E + (3 * BKT + 4) * K + 64;

    // workspace layout (keep 16-B alignment for b128 reads)
    __half* g1h     = (__half*)d_ws;                      // (N+1)*64 halves
    __half* th      = g1h + (size_t)(N + 1) * DD;         // TBL halves
    __half* w1t     = th + TBL;                           // 4096 halves
    __half* w2t     = w1t + DD * DD;                      // 4096 halves
    int*    pairbuf = (int*)(w2t + DD * DD);              // E ints
    int*    csr_src = pairbuf + E;                        // CSRSZ ints
    int2*   rowinfo = (int2*)(csr_src + CSRSZ);           // N int2
    float2* xd      = (float2*)(rowinfo + N);             // N+1 float2
    __half* dinvh   = (__half*)(xd + N + 1);              // N+1 halves (pad even)
    float*  outacc  = (float*)(dinvh + (size_t)((N + 2) & ~1)); // 2G
    int*    pbase   = (int*)(outacc + 2 * G);             // K
    int*    pcnt    = pbase + K;                          // K
    int*    cbase   = pcnt + K;                           // K
    int*    pcur    = cbase + K;                          // 1
    int*    ccur    = pcur + 1;                           // 1 (+2 pad)
    int*    hist    = ccur + 3;                           // M
    int*    cur     = hist + M;                           // M

    const int BT = 256;

    // partition: histogram(+zeros) -> alloc -> append -> CSR sort
    bin_count_kernel<<<NBLK, BTE, 0, stream>>>(dst, E, CH, hist, K,
                                               (const float2*)table,
                                               (__half2*)th, TBL / 2,
                                               W1, W2, w1t, w2t,
                                               outacc, 2 * G, pcur, ccur);
    alloc_kernel<<<(K * 64 + BT - 1) / BT, BT, 0, stream>>>(hist, cur, pbase,
                                                            pcnt, cbase, pcur,
                                                            ccur, K);
    fill_kernel<<<NBLK, BTE, 0, stream>>>(src, dst, E, CH, cur, pairbuf, K);
    build_csr_kernel<<<K, BT, 0, stream>>>(pairbuf, pbase, pcnt, cbase, x,
                                           rowinfo, xd, dinvh, csr_src, g1h, N);

    // layer 1 (embed+agg+MFMA-MLP+relu fused; writes g1h = fp16(dinv*h1))
    int gRow = (N + 31) / 32;
    layer1_kernel<<<gRow, BT, 0, stream>>>(rowinfo, csr_src, xd, dinvh,
                                           (const float4*)th, w1t, b1, g1h, N);
    // layer 2 (agg+MFMA-MLP+relu+pool fused)
    layer2_pool_kernel<<<gRow, BT, 0, stream>>>(rowinfo, csr_src, xd,
                                                (const float4*)g1h, w2t, b2,
                                                batch, Wlin, outacc, N);
    // final
    final_kernel<<<(G * 2 + BT - 1) / BT, BT, 0, stream>>>(outacc, batch, blin,
                                                           out, G, N);
}

// Round 7
// 213.417 us; speedup vs baseline: 3.1835x; 1.0801x over previous
//
#include <hip/hip_runtime.h>
#include <hip/hip_fp16.h>

// ---------------------------------------------------------------------------
// GCN forward on MI355X — round 25.
//  * R24 post-mortem: alloc-merge alone = 230.5 vs R21's 218.2 — atomic
//    region allocation permutes the bucket arena (R21's scan kept it
//    bucket-ordered) and costs more than two launch overheads.  Partition
//    reverted to EXACT R21 (bin_count -> totals -> scan_bb -> scanB -> fill
//    -> build_csr with LDS-staged slices).
//  * Forward delta (isolated, layers only): load ALL of a node's csr quads
//    (c0..c3, covers deg<=16 = 99.6% of Poisson(8)) at loop ENTRY, then run
//    the gather/FMA bodies from registers.  The runtime trip count blocked
//    compiler hoisting, so each quad-pair paid a serialized ~200-400cy L2
//    latency; now it's paid once per node.  Unlike R23's failed rotation,
//    there is NO loop-carried dependency.  Tail (deg>16) loops from memory.
// ---------------------------------------------------------------------------

#define DD 64          // feature dim
#define BKT 256        // nodes per bucket (CSR build)
#define MAXK 1024      // max buckets; hist/cur row stride
#define NBLK 256       // partition blocks (chunks)
#define SLACK 772      // per-bucket csr slack: 3*256 pad + 4 alignment
#define BTE 1024       // threads/block for per-edge passes
#define SRCMASK 0x3FFFF  // low 18 bits = src node id
#define PBUF_CAP 4096  // LDS staging capacity for one bucket's pair slice

typedef _Float16 half8_t __attribute__((ext_vector_type(8)));
typedef float float4_t __attribute__((ext_vector_type(4)));
union F4H8 { float4 f; half8_t h; };
union H8   { float4 f; __half2 h[4]; };

static __device__ __forceinline__ void atomAddF(float* p, float v) {
    unsafeAtomicAdd(p, v);   // global_atomic_add_f32 on gfx950
}

// ---- pass A: per-chunk histogram (+ fp16 conversions piggy-backed) --------
__global__ __launch_bounds__(BTE) void bin_count_kernel(
        const int* __restrict__ dst, int E, int CH,
        int* __restrict__ hist, int K,
        const float2* __restrict__ table2, __half2* __restrict__ th2, int n2,
        const float* __restrict__ W1, const float* __restrict__ W2,
        __half* __restrict__ w1t, __half* __restrict__ w2t) {
    __shared__ int lh[MAXK];
    int tid = threadIdx.x;
    for (int i = tid; i < K; i += BTE) lh[i] = 0;
    __syncthreads();
    int stride = gridDim.x * BTE;
    for (int i = blockIdx.x * BTE + tid; i < n2; i += stride)
        th2[i] = __float22half2_rn(table2[i]);
    for (int i = blockIdx.x * BTE + tid; i < DD * DD; i += stride) {
        int n = i >> 6, k = i & 63;
        w1t[i] = __float2half(W1[k * DD + n]);   // WT[n][k]
        w2t[i] = __float2half(W2[k * DD + n]);
    }
    int e0 = blockIdx.x * CH;
    int e1 = min(E, e0 + CH);
    for (int e = e0 + tid; e < e1; e += BTE)
        atomicAdd(&lh[((unsigned)dst[e]) >> 8], 1);
    __syncthreads();
    for (int b = tid; b < K; b += BTE)
        hist[blockIdx.x * MAXK + b] = lh[b];     // coalesced private row
}

// ---- pass B0: bucket totals, one WAVE per bucket; zero outacc -------------
__global__ __launch_bounds__(256) void totals_kernel(
        const int* __restrict__ hist, int* __restrict__ bts,
        float* __restrict__ outacc, int K, int G2) {
    int gt = blockIdx.x * 256 + threadIdx.x;
    if (gt < G2) outacc[gt] = 0.f;
    int wid = gt >> 6;            // wave id = bucket
    int lane = threadIdx.x & 63;
    if (wid >= K) return;
    const int PER = NBLK / 64;    // 4 cells per lane
    int s = 0;
    #pragma unroll
    for (int i = 0; i < PER; ++i)
        s += hist[(lane * PER + i) * MAXK + wid];
    #pragma unroll
    for (int off = 32; off >= 1; off >>= 1)
        s += __shfl_xor(s, off);
    if (lane == 0) bts[wid] = s;
}

// ---- pass B1: exclusive scan of bts[K] -> bb; bb[K] = E -------------------
__global__ __launch_bounds__(256) void scan_bb_kernel(
        const int* __restrict__ bts, int* __restrict__ bb, int K, int E) {
    __shared__ int part[256];
    int tid = threadIdx.x;
    int CH2 = (K + 255) / 256;
    int base = tid * CH2;
    int s = 0;
    for (int i = 0; i < CH2; ++i) {
        int idx = base + i;
        if (idx < K) s += bts[idx];
    }
    part[tid] = s;
    __syncthreads();
    if (tid < 64) {
        int carry = 0;
        for (int c = 0; c < 4; ++c) {
            int orig = part[c * 64 + tid];
            int v = orig;
            #pragma unroll
            for (int off = 1; off < 64; off <<= 1) {
                int t = __shfl_up(v, off);
                if (tid >= off) v += t;
            }
            int tot = __shfl(v, 63);
            part[c * 64 + tid] = v - orig + carry;   // exclusive
            carry += tot;
        }
    }
    __syncthreads();
    int run = part[tid];
    for (int i = 0; i < CH2; ++i) {
        int idx = base + i;
        if (idx < K) {
            bb[idx] = run;
            run += bts[idx];
        }
    }
    if (tid == 0) bb[K] = E;
}

// ---- pass B2: one WAVE per bucket scans across blocks -> cur[blk][bucket] -
__global__ __launch_bounds__(256) void scanB_kernel(
        const int* __restrict__ hist, const int* __restrict__ bb,
        int* __restrict__ cur, int K) {
    int wid = (blockIdx.x * 256 + threadIdx.x) >> 6;   // global wave id = bucket
    int lane = threadIdx.x & 63;
    if (wid >= K) return;
    int b = wid;
    const int PER = NBLK / 64;    // 4 blocks per lane
    int v[PER];
    int sum = 0;
    #pragma unroll
    for (int i = 0; i < PER; ++i) {
        v[i] = hist[(lane * PER + i) * MAXK + b];
        sum += v[i];
    }
    int pref = sum;
    #pragma unroll
    for (int off = 1; off < 64; off <<= 1) {
        int t = __shfl_up(pref, off);
        if (lane >= off) pref += t;
    }
    int run = bb[b] + pref - sum;   // exclusive
    #pragma unroll
    for (int i = 0; i < PER; ++i) {
        cur[(lane * PER + i) * MAXK + b] = run;
        run += v[i];
    }
}

// ---- pass C: append packed pairs; cursors in LDS (block-private cells) ----
__global__ __launch_bounds__(BTE) void fill_kernel(
        const int* __restrict__ src, const int* __restrict__ dst, int E, int CH,
        const int* __restrict__ cur, int* __restrict__ pairbuf, int K) {
    __shared__ int lcur[MAXK];
    int tid = threadIdx.x;
    for (int b = tid; b < K; b += BTE)
        lcur[b] = cur[blockIdx.x * MAXK + b];
    __syncthreads();
    int e0 = blockIdx.x * CH;
    int e1 = min(E, e0 + CH);
    for (int e = e0 + tid; e < e1; e += BTE) {
        int s = src[e], d = dst[e];
        int pos = atomicAdd(&lcur[((unsigned)d) >> 8], 1);
        pairbuf[pos] = s | ((d & 255) << 24);
    }
}

// ---- pass D: per-bucket padded CSR build from LDS-staged slice ------------
// csr entry = src | (x[src] << 18): layer1 decodes the embedding row directly,
// layer2 masks with SRCMASK.  Sentinel pad = N (x-part 0 -> zeroed th row 0,
// dinvh[N] = 0 -> zero weight, g1h row N zeroed -> zero layer2 term).
__global__ __launch_bounds__(256) void build_csr_kernel(
        const int* __restrict__ pairbuf, const int* __restrict__ bnd,
        const int* __restrict__ x, int2* __restrict__ rowinfo,
        float2* __restrict__ xd, __half* __restrict__ dinvh,
        int* __restrict__ csr_src, __half* __restrict__ g1h, int N) {
    __shared__ int cnt[256], basel[256], curl[256];
    __shared__ int pbuf[PBUF_CAP];
    int tid = threadIdx.x;
    int b = blockIdx.x;
    int node0 = b << 8;
    cnt[tid] = 0;
    __syncthreads();
    int bb0 = bnd[b], bb1 = bnd[b + 1];
    int L = bb1 - bb0;
    bool fits = (L <= PBUF_CAP);
    if (fits) {
        for (int i = tid; i < L; i += 256) {
            int pk = pairbuf[bb0 + i];
            pbuf[i] = pk;
            atomicAdd(&cnt[((unsigned)pk) >> 24], 1);
        }
    } else {
        for (int i = bb0 + tid; i < bb1; i += 256)
            atomicAdd(&cnt[((unsigned)pairbuf[i]) >> 24], 1);
    }
    __syncthreads();
    int c  = cnt[tid];
    int pc = (c + 3) & ~3;              // padded count
    {
        __syncthreads();
        basel[tid] = pc;
        __syncthreads();
        if (tid < 64) {
            int carry = 0;
            for (int cc = 0; cc < 4; ++cc) {
                int orig = basel[cc * 64 + tid];
                int v = orig;
                #pragma unroll
                for (int off = 1; off < 64; off <<= 1) {
                    int t = __shfl_up(v, off);
                    if (tid >= off) v += t;
                }
                int tot = __shfl(v, 63);
                cnt[cc * 64 + tid] = v - orig + carry;   // exclusive
                carry += tot;
            }
        }
        __syncthreads();
    }
    int cb0 = ((bb0 + 3) & ~3) + SLACK * b;   // aligned csr base for bucket
    int node = node0 + tid;
    int myBase = cb0 + cnt[tid];
    curl[tid] = myBase;
    if (node < N) {
        rowinfo[node] = make_int2(myBase, pc);
        float di = rsqrtf((float)c + 1.0f);
        xd[node] = make_float2(di, __int_as_float(x[node]));
        dinvh[node] = __float2half(di);
        for (int t = c; t < pc; ++t) csr_src[myBase + t] = N;   // sentinel pad
    } else if (node == N) {
        xd[N] = make_float2(0.0f, __int_as_float(0));           // zero weight
        dinvh[N] = __float2half(0.0f);
        float2* z = (float2*)(g1h + (size_t)N * DD);            // zero row N
        for (int t = 0; t < DD / 4; ++t) z[t] = make_float2(0.f, 0.f);
    }
    __syncthreads();
    if (fits) {
        for (int i = tid; i < L; i += 256) {
            int pk = pbuf[i];
            int pos = atomicAdd(&curl[((unsigned)pk) >> 24], 1);
            int s = pk & 0x00FFFFFF;
            csr_src[pos] = (int)(((unsigned)s) | (((unsigned)x[s]) << 18));
        }
    } else {
        for (int i = bb0 + tid; i < bb1; i += 256) {
            int pk = pairbuf[i];
            int pos = atomicAdd(&curl[((unsigned)pk) >> 24], 1);
            int s = pk & 0x00FFFFFF;
            csr_src[pos] = (int)(((unsigned)s) | (((unsigned)x[s]) << 18));
        }
    }
}

// ---------------- layer 1: agg from fp16 table, MFMA MLP, g1h = f16(dv*h1) --
// 8 lanes/node, b128 chunks; Hs stride 9 (bank-conflict pad).
// All csr quads (c0..c3) loaded at entry — cs L2 latency paid once per node.
#define L1_BODY4(sA)                                                          \
    do {                                                                      \
        unsigned a0 = (unsigned)(sA).x, a1 = (unsigned)(sA).y;                \
        unsigned a2 = (unsigned)(sA).z, a3 = (unsigned)(sA).w;                \
        H8 u0, u1, u2, u3;                                                    \
        u0.f = th4[(size_t)(a0 >> 18) * 8 + j3];                              \
        u1.f = th4[(size_t)(a1 >> 18) * 8 + j3];                              \
        u2.f = th4[(size_t)(a2 >> 18) * 8 + j3];                              \
        u3.f = th4[(size_t)(a3 >> 18) * 8 + j3];                              \
        __half2 w0 = __half2half2(dinvh[a0 & SRCMASK]);                       \
        __half2 w1 = __half2half2(dinvh[a1 & SRCMASK]);                       \
        __half2 w2 = __half2half2(dinvh[a2 & SRCMASK]);                       \
        __half2 w3 = __half2half2(dinvh[a3 & SRCMASK]);                       \
        _Pragma("unroll")                                                     \
        for (int t = 0; t < 4; ++t) {                                         \
            acc0.h[t] = __hfma2(w0, u0.h[t], acc0.h[t]);                      \
            acc1.h[t] = __hfma2(w1, u1.h[t], acc1.h[t]);                      \
            acc2.h[t] = __hfma2(w2, u2.h[t], acc2.h[t]);                      \
            acc3.h[t] = __hfma2(w3, u3.h[t], acc3.h[t]);                      \
        }                                                                     \
    } while (0)

__global__ __launch_bounds__(256, 8) void layer1_kernel(
        const int2* __restrict__ rowinfo,
        const int* __restrict__ csr_src, const float2* __restrict__ xd,
        const __half* __restrict__ dinvh,
        const float4* __restrict__ th4, const __half* __restrict__ wt,
        const float* __restrict__ bias, __half* __restrict__ g1h, int N) {
    __shared__ float4 Hs4[32 * 9];   // padded stride 9
    __shared__ float dvs[32];
    int row0 = blockIdx.x * 32;
    int tid = threadIdx.x;
    int node_l = tid >> 3, j3 = tid & 7;
    int node = row0 + node_l;
    H8 acc0, acc1, acc2, acc3;
    acc0.f = make_float4(0.f, 0.f, 0.f, 0.f);
    acc1.f = acc0.f; acc2.f = acc0.f; acc3.f = acc0.f;
    __half2 dh = __float2half2_rn(0.f);
    if (node < N) {
        float2 sxd = xd[node];
        float di = sxd.x;
        if (j3 == 0) dvs[node_l] = di;
        dh = __float2half2_rn(di);
        int2 ri = rowinfo[node];
        const int4* cs = (const int4*)(csr_src + ri.x);
        int nq = ri.y >> 2;
        int4 c0 = {0, 0, 0, 0}, c1 = c0, c2 = c0, c3 = c0;
        if (nq > 0) c0 = cs[0];
        if (nq > 1) c1 = cs[1];
        if (nq > 2) c2 = cs[2];
        if (nq > 3) c3 = cs[3];
        H8 tv; tv.f = th4[(size_t)__float_as_int(sxd.y) * 8 + j3];
        acc0.h[0] = __hmul2(dh, tv.h[0]); acc0.h[1] = __hmul2(dh, tv.h[1]);
        acc0.h[2] = __hmul2(dh, tv.h[2]); acc0.h[3] = __hmul2(dh, tv.h[3]);
        if (nq > 0) L1_BODY4(c0);
        if (nq > 1) L1_BODY4(c1);
        if (nq > 2) L1_BODY4(c2);
        if (nq > 3) L1_BODY4(c3);
        for (int q = 4; q < nq; ++q) {   // rare tail: deg > 16
            int4 cq = cs[q];
            L1_BODY4(cq);
        }
        #pragma unroll
        for (int t = 0; t < 4; ++t)
            acc0.h[t] = __hmul2(dh, __hadd2(__hadd2(acc0.h[t], acc1.h[t]),
                                            __hadd2(acc2.h[t], acc3.h[t])));
    }
    Hs4[node_l * 9 + j3] = acc0.f;
    __syncthreads();

    // MFMA MLP: 2 tiles of 16 rows; each wave does cols wave*16..+15, K=64.
    int wave = tid >> 6, lane = tid & 63;
    int m = lane & 15, quad = lane >> 4;
    int ncol = wave * 16 + m;
    F4H8 b0, b1;
    const float4* WT4 = (const float4*)wt;
    b0.f = WT4[ncol * 8 + quad];
    b1.f = WT4[ncol * 8 + 4 + quad];
    float bb_ = bias[ncol];
    #pragma unroll
    for (int t = 0; t < 2; ++t) {
        F4H8 a0, a1;
        a0.f = Hs4[(t * 16 + m) * 9 + quad];
        a1.f = Hs4[(t * 16 + m) * 9 + 4 + quad];
        float4_t acc = {0.f, 0.f, 0.f, 0.f};
        acc = __builtin_amdgcn_mfma_f32_16x16x32_f16(a0.h, b0.h, acc, 0, 0, 0);
        acc = __builtin_amdgcn_mfma_f32_16x16x32_f16(a1.h, b1.h, acc, 0, 0, 0);
        #pragma unroll
        for (int reg = 0; reg < 4; ++reg) {
            int row = t * 16 + quad * 4 + reg;
            int grow = row0 + row;
            if (grow < N) {
                float h = fmaxf(acc[reg] + bb_, 0.0f);
                g1h[(size_t)grow * DD + ncol] = __float2half(dvs[row] * h);
            }
        }
    }
}

// -------- layer 2 + pool: gather g1h, MFMA MLP, Wlin dot + segmented pool ---
#define L2_BODY4(sA)                                                          \
    do {                                                                      \
        H8 u0, u1, u2, u3;                                                    \
        u0.f = g1h4[(size_t)((sA).x & SRCMASK) * 8 + j3];                     \
        u1.f = g1h4[(size_t)((sA).y & SRCMASK) * 8 + j3];                     \
        u2.f = g1h4[(size_t)((sA).z & SRCMASK) * 8 + j3];                     \
        u3.f = g1h4[(size_t)((sA).w & SRCMASK) * 8 + j3];                     \
        _Pragma("unroll")                                                     \
        for (int t = 0; t < 4; ++t) {                                         \
            acc0.h[t] = __hadd2(acc0.h[t], u0.h[t]);                          \
            acc1.h[t] = __hadd2(acc1.h[t], u1.h[t]);                          \
            acc2.h[t] = __hadd2(acc2.h[t], u2.h[t]);                          \
            acc3.h[t] = __hadd2(acc3.h[t], u3.h[t]);                          \
        }                                                                     \
    } while (0)

__global__ __launch_bounds__(256, 8) void layer2_pool_kernel(
        const int2* __restrict__ rowinfo,
        const int* __restrict__ csr_src, const float2* __restrict__ xd,
        const float4* __restrict__ g1h4, const __half* __restrict__ wt,
        const float* __restrict__ bias, const int* __restrict__ batch,
        const float* __restrict__ Wlin, float* __restrict__ outacc, int N) {
    __shared__ float4 Hs4[32 * 9];       // padded stride 9
    __shared__ float lp0[128], lp1[128]; // [wave][row]
    __shared__ float p0s[32], p1s[32];
    __shared__ int   bat[32];
    int row0 = blockIdx.x * 32;
    int tid = threadIdx.x;
    int node_l = tid >> 3, j3 = tid & 7;
    int node = row0 + node_l;
    H8 acc0, acc1, acc2, acc3;
    acc0.f = make_float4(0.f, 0.f, 0.f, 0.f);
    acc1.f = acc0.f; acc2.f = acc0.f; acc3.f = acc0.f;
    if (node < N) {
        float di = xd[node].x;
        int2 ri = rowinfo[node];
        const int4* cs = (const int4*)(csr_src + ri.x);
        int nq = ri.y >> 2;
        int4 c0 = {0, 0, 0, 0}, c1 = c0, c2 = c0, c3 = c0;
        if (nq > 0) c0 = cs[0];
        if (nq > 1) c1 = cs[1];
        if (nq > 2) c2 = cs[2];
        if (nq > 3) c3 = cs[3];
        acc0.f = g1h4[(size_t)node * 8 + j3];   // self term, weight 1
        if (nq > 0) L2_BODY4(c0);
        if (nq > 1) L2_BODY4(c1);
        if (nq > 2) L2_BODY4(c2);
        if (nq > 3) L2_BODY4(c3);
        for (int q = 4; q < nq; ++q) {   // rare tail: deg > 16
            int4 cq = cs[q];
            L2_BODY4(cq);
        }
        __half2 dih = __float2half2_rn(di);
        #pragma unroll
        for (int t = 0; t < 4; ++t)
            acc0.h[t] = __hmul2(dih, __hadd2(__hadd2(acc0.h[t], acc1.h[t]),
                                             __hadd2(acc2.h[t], acc3.h[t])));
    }
    Hs4[node_l * 9 + j3] = acc0.f;
    __syncthreads();

    int wave = tid >> 6, lane = tid & 63;
    int m = lane & 15, quad = lane >> 4;
    int ncol = wave * 16 + m;
    F4H8 b0, b1;
    const float4* WT4 = (const float4*)wt;
    b0.f = WT4[ncol * 8 + quad];
    b1.f = WT4[ncol * 8 + 4 + quad];
    float bb_  = bias[ncol];
    float wl0 = Wlin[ncol * 2 + 0];
    float wl1 = Wlin[ncol * 2 + 1];
    #pragma unroll
    for (int t = 0; t < 2; ++t) {
        F4H8 a0, a1;
        a0.f = Hs4[(t * 16 + m) * 9 + quad];
        a1.f = Hs4[(t * 16 + m) * 9 + 4 + quad];
        float4_t acc = {0.f, 0.f, 0.f, 0.f};
        acc = __builtin_amdgcn_mfma_f32_16x16x32_f16(a0.h, b0.h, acc, 0, 0, 0);
        acc = __builtin_amdgcn_mfma_f32_16x16x32_f16(a1.h, b1.h, acc, 0, 0, 0);
        #pragma unroll
        for (int reg = 0; reg < 4; ++reg) {
            int row = t * 16 + quad * 4 + reg;
            int grow = row0 + row;
            float h = (grow < N) ? fmaxf(acc[reg] + bb_, 0.0f) : 0.0f;
            float p0 = h * wl0;
            float p1 = h * wl1;
            #pragma unroll
            for (int off = 8; off >= 1; off >>= 1) {   // sum over 16 cols (m)
                p0 += __shfl_xor(p0, off);
                p1 += __shfl_xor(p1, off);
            }
            if (m == 0) {
                lp0[wave * 32 + row] = p0;
                lp1[wave * 32 + row] = p1;
            }
        }
    }
    __syncthreads();
    if (tid < 32) {
        int grow = row0 + tid;
        p0s[tid] = lp0[tid] + lp0[32 + tid] + lp0[64 + tid] + lp0[96 + tid];
        p1s[tid] = lp1[tid] + lp1[32 + tid] + lp1[64 + tid] + lp1[96 + tid];
        bat[tid] = (grow < N) ? batch[grow] : -1;
    }
    __syncthreads();
    if (tid < 32) {
        int bg = bat[tid];
        bool head = (bg >= 0) && (tid == 0 || bat[tid - 1] != bg);
        if (head) {
            float s0 = 0.f, s1 = 0.f;
            for (int k = tid; k < 32 && bat[k] == bg; ++k) {
                s0 += p0s[k];
                s1 += p1s[k];
            }
            atomAddF(&outacc[bg * 2 + 0], s0);
            atomAddF(&outacc[bg * 2 + 1], s1);
        }
    }
}

// counts via binary search on sorted batch; then divide + blin
__global__ void final_kernel(const float* __restrict__ outacc,
                             const int* __restrict__ batch,
                             const float* __restrict__ blin,
                             float* __restrict__ out, int G, int N) {
    int t = blockIdx.x * blockDim.x + threadIdx.x;
    if (t >= G * 2) return;
    int g = t >> 1, c = t & 1;
    int lo = 0, hi = N;
    while (lo < hi) { int m = (lo + hi) >> 1; if (batch[m] < g) lo = m + 1; else hi = m; }
    int lo2 = lo, hi2 = N;
    while (lo2 < hi2) { int m = (lo2 + hi2) >> 1; if (batch[m] < g + 1) lo2 = m + 1; else hi2 = m; }
    float cnt = (float)(lo2 - lo);
    out[t] = outacc[t] / fmaxf(cnt, 1.0f) + blin[c];
}

extern "C" void kernel_launch(void* const* d_in, const int* in_sizes, int n_in,
                              void* d_out, int out_size, void* d_ws, size_t ws_size,
                              hipStream_t stream) {
    const int*   x      = (const int*)d_in[0];
    const int*   ei     = (const int*)d_in[1];   // [2,E] row-major
    const int*   batch  = (const int*)d_in[3];
    const float* table  = (const float*)d_in[4];
    const float* W1     = (const float*)d_in[5];
    const float* b1     = (const float*)d_in[6];
    const float* W2     = (const float*)d_in[7];
    const float* b2     = (const float*)d_in[8];
    const float* Wlin   = (const float*)d_in[9];
    const float* blin   = (const float*)d_in[10];
    float* out = (float*)d_out;

    const int N = in_sizes[0];
    const int E = in_sizes[2];          // edge_type count == E
    const int G = out_size / 2;
    const int TBL = in_sizes[4];        // VOCAB*DD floats

    const int* src = ei;
    const int* dst = ei + E;

    const int K = (N + BKT - 1) / BKT;  // buckets
    const int M = NBLK * MAXK;          // (block, bucket) cells
    const int CH = (E + NBLK - 1) / NBLK;
    const int CSRSZ = E + SLACK * K + 64;

    // workspace layout (keep 16-B alignment for b128 reads)
    __half* g1h     = (__half*)d_ws;                      // (N+1)*64 halves
    __half* th      = g1h + (size_t)(N + 1) * DD;         // TBL halves
    __half* w1t     = th + TBL;                           // 4096 halves
    __half* w2t     = w1t + DD * DD;                      // 4096 halves
    int*    pairbuf = (int*)(w2t + DD * DD);              // E ints
    int*    csr_src = pairbuf + E;                        // CSRSZ ints
    int2*   rowinfo = (int2*)(csr_src + CSRSZ);           // N int2
    float2* xd      = (float2*)(rowinfo + N);             // N+1 float2
    __half* dinvh   = (__half*)(xd + N + 1);              // N+1 halves (pad even)
    float*  outacc  = (float*)(dinvh + (size_t)((N + 2) & ~1)); // 2G
    int*    bb      = (int*)(outacc + 2 * G);             // K+1
    int*    bts     = bb + K + 1;                         // K
    int*    hist    = bts + K;                            // M
    int*    cur     = hist + M;                           // M

    const int BT = 256;

    // partition: per-chunk histogram -> wave-totals(+outacc zero) -> bucket
    //            scan -> per-bucket block scan -> append -> CSR sort
    bin_count_kernel<<<NBLK, BTE, 0, stream>>>(dst, E, CH, hist, K,
                                               (const float2*)table,
                                               (__half2*)th, TBL / 2,
                                               W1, W2, w1t, w2t);
    totals_kernel<<<(K * 64 + BT - 1) / BT, BT, 0, stream>>>(hist, bts, outacc,
                                                             K, 2 * G);
    scan_bb_kernel<<<1, BT, 0, stream>>>(bts, bb, K, E);
    scanB_kernel<<<(K * 64 + BT - 1) / BT, BT, 0, stream>>>(hist, bb, cur, K);
    fill_kernel<<<NBLK, BTE, 0, stream>>>(src, dst, E, CH, cur, pairbuf, K);
    build_csr_kernel<<<K, BT, 0, stream>>>(pairbuf, bb, x, rowinfo, xd, dinvh,
                                           csr_src, g1h, N);

    // layer 1 (embed+agg+MFMA-MLP+relu fused; writes g1h = fp16(dinv*h1))
    int gRow = (N + 31) / 32;
    layer1_kernel<<<gRow, BT, 0, stream>>>(rowinfo, csr_src, xd, dinvh,
                                           (const float4*)th, w1t, b1, g1h, N);
    // layer 2 (agg+MFMA-MLP+relu+pool fused)
    layer2_pool_kernel<<<gRow, BT, 0, stream>>>(rowinfo, csr_src, xd,
                                                (const float4*)g1h, w2t, b2,
                                                batch, Wlin, outacc, N);
    // final
    final_kernel<<<(G * 2 + BT - 1) / BT, BT, 0, stream>>>(outacc, batch, blin,
                                                           out, G, N);
}